// Round 2
// baseline (2923.844 us; speedup 1.0000x reference)
//
#include <hip/hip_runtime.h>

#define NF 128   // F_IN == F_OUT == 128

// ---------------------------------------------------------------------------
// Kernel 1: agg = (1+eps)*x ; zero the BN stats accumulators (512 floats)
// ---------------------------------------------------------------------------
__global__ void init_kernel(const float* __restrict__ x, const float* __restrict__ eps,
                            float* __restrict__ agg, float* __restrict__ stats, int total4) {
    int gid = blockIdx.x * blockDim.x + threadIdx.x;
    if (gid < 512) stats[gid] = 0.0f;
    if (gid >= total4) return;
    float s = 1.0f + eps[0];
    float4 v = reinterpret_cast<const float4*>(x)[gid];
    v.x *= s; v.y *= s; v.z *= s; v.w *= s;
    reinterpret_cast<float4*>(agg)[gid] = v;
}

// ---------------------------------------------------------------------------
// Kernel 2: edge scatter-add. 32 threads per edge, float4 gather + 4 atomics.
// NOTE: harness delivers integer inputs as int32 (even though ref is int64).
// ---------------------------------------------------------------------------
__global__ void scatter_kernel(const float* __restrict__ x, const int* __restrict__ ei,
                               float* __restrict__ agg, int E) {
    long long gid = (long long)blockIdx.x * blockDim.x + threadIdx.x;
    int e = (int)(gid >> 5);
    if (e >= E) return;
    int c = ((int)gid & 31) << 2;
    int row = ei[e];
    int col = ei[E + e];
    const float4 v = *reinterpret_cast<const float4*>(x + (long long)col * NF + c);
    float* dst = agg + (long long)row * NF + c;
    unsafeAtomicAdd(dst + 0, v.x);
    unsafeAtomicAdd(dst + 1, v.y);
    unsafeAtomicAdd(dst + 2, v.z);
    unsafeAtomicAdd(dst + 3, v.w);
}

// ---------------------------------------------------------------------------
// Kernels 3&5: fp32 SGEMM  out[n][j] = sum_k A[n][k]*W[j][k] + bias[j]
// Block tile 64 rows x 128 cols, 256 threads, 4x8 micro-tile, K chunked by 16.
// MODE 0: plain A, accumulate per-feature sum/sumsq into stats (BN training).
// MODE 1: A-load transform relu(a*scale[k]+shift[k]); in-place safe (each
//         block reads only its own 64 rows fully before writing them).
// ---------------------------------------------------------------------------
template <int MODE>
__global__ __launch_bounds__(256) void gemm_kernel(
    const float* __restrict__ A, const float* __restrict__ W,
    const float* __restrict__ bias, float* __restrict__ out,
    float* __restrict__ stats, const float* __restrict__ scale,
    const float* __restrict__ shift, int N) {
    __shared__ float As[16][68];    // [k][row], padded
    __shared__ float Bs[16][132];   // [k][col], padded
    __shared__ float red[16][128];  // BN stats block reduction

    const int t = threadIdx.x;
    const int row0 = blockIdx.x * 64;
    const int ty = t >> 4;   // 0..15 -> rows ty*4 .. ty*4+3
    const int tx = t & 15;   // 0..15 -> cols tx*8 .. tx*8+7

    float acc[4][8];
#pragma unroll
    for (int i = 0; i < 4; i++)
#pragma unroll
        for (int j = 0; j < 8; j++) acc[i][j] = 0.0f;

    for (int kt = 0; kt < 8; kt++) {
        // ---- stage A tile: 64 rows x 16 k (one float4 per thread) ----
        {
            int row = t >> 2;
            int kq = t & 3;
            int r = row0 + row;
            float4 v = make_float4(0.f, 0.f, 0.f, 0.f);
            if (r < N)
                v = *reinterpret_cast<const float4*>(A + (long long)r * NF + kt * 16 + kq * 4);
            float vv[4] = {v.x, v.y, v.z, v.w};
            if (MODE == 1) {
#pragma unroll
                for (int i = 0; i < 4; i++) {
                    int k = kt * 16 + kq * 4 + i;
                    vv[i] = fmaxf(vv[i] * scale[k] + shift[k], 0.0f);
                }
            }
#pragma unroll
            for (int i = 0; i < 4; i++) As[kq * 4 + i][row] = vv[i];
        }
        // ---- stage B tile: 128 cols x 16 k (two float4 per thread) ----
#pragma unroll
        for (int l = 0; l < 2; l++) {
            int li = t + l * 256;
            int j = li >> 2;
            int kq = li & 3;
            float4 w = *reinterpret_cast<const float4*>(W + j * NF + kt * 16 + kq * 4);
            float wv[4] = {w.x, w.y, w.z, w.w};
#pragma unroll
            for (int i = 0; i < 4; i++) Bs[kq * 4 + i][j] = wv[i];
        }
        __syncthreads();
        // ---- compute ----
#pragma unroll
        for (int kk = 0; kk < 16; kk++) {
            float4 a = *reinterpret_cast<const float4*>(&As[kk][ty * 4]);
            float4 b0 = *reinterpret_cast<const float4*>(&Bs[kk][tx * 8]);
            float4 b1 = *reinterpret_cast<const float4*>(&Bs[kk][tx * 8 + 4]);
            float av[4] = {a.x, a.y, a.z, a.w};
            float bv[8] = {b0.x, b0.y, b0.z, b0.w, b1.x, b1.y, b1.z, b1.w};
#pragma unroll
            for (int i = 0; i < 4; i++)
#pragma unroll
                for (int j = 0; j < 8; j++) acc[i][j] = fmaf(av[i], bv[j], acc[i][j]);
        }
        __syncthreads();
    }

    // ---- epilogue: add bias, store ----
    const int c0 = tx * 8;
    float h[4][8];
#pragma unroll
    for (int i = 0; i < 4; i++) {
        int r = row0 + ty * 4 + i;
#pragma unroll
        for (int j = 0; j < 8; j++) h[i][j] = acc[i][j] + bias[c0 + j];
        if (r < N) {
            float4 s0 = make_float4(h[i][0], h[i][1], h[i][2], h[i][3]);
            float4 s1 = make_float4(h[i][4], h[i][5], h[i][6], h[i][7]);
            *reinterpret_cast<float4*>(out + (long long)r * NF + c0) = s0;
            *reinterpret_cast<float4*>(out + (long long)r * NF + c0 + 4) = s1;
        }
    }

    if (MODE == 0) {
        // per-feature partial sum / sumsq over this block's valid rows
        float s8[8], q8[8];
#pragma unroll
        for (int j = 0; j < 8; j++) { s8[j] = 0.f; q8[j] = 0.f; }
#pragma unroll
        for (int i = 0; i < 4; i++) {
            int r = row0 + ty * 4 + i;
            if (r < N) {
#pragma unroll
                for (int j = 0; j < 8; j++) {
                    s8[j] += h[i][j];
                    q8[j] += h[i][j] * h[i][j];
                }
            }
        }
#pragma unroll
        for (int j = 0; j < 8; j++) red[ty][c0 + j] = s8[j];
        __syncthreads();
        if (t < 128) {
            float tot = 0.f;
#pragma unroll
            for (int y = 0; y < 16; y++) tot += red[y][t];
            unsafeAtomicAdd(&stats[t], tot);
        }
        __syncthreads();
#pragma unroll
        for (int j = 0; j < 8; j++) red[ty][c0 + j] = q8[j];
        __syncthreads();
        if (t < 128) {
            float tot = 0.f;
#pragma unroll
            for (int y = 0; y < 16; y++) tot += red[y][t];
            unsafeAtomicAdd(&stats[128 + t], tot);
        }
    }
}

// ---------------------------------------------------------------------------
// Kernel 4: BN finalize -> per-feature scale/shift
// ---------------------------------------------------------------------------
__global__ void bn_finalize(const float* __restrict__ stats, const float* __restrict__ gamma,
                            const float* __restrict__ beta, float* __restrict__ scale,
                            float* __restrict__ shift, int N) {
    int f = threadIdx.x;
    if (f >= NF) return;
    float inv_n = 1.0f / (float)N;
    float mean = stats[f] * inv_n;
    float var = fmaxf(stats[128 + f] * inv_n - mean * mean, 0.0f);
    float s = gamma[f] * rsqrtf(var + 1e-5f);
    scale[f] = s;
    shift[f] = beta[f] - mean * s;
}

extern "C" void kernel_launch(void* const* d_in, const int* in_sizes, int n_in,
                              void* d_out, int out_size, void* d_ws, size_t ws_size,
                              hipStream_t stream) {
    const float* x          = (const float*)d_in[0];
    const int* ei           = (const int*)d_in[1];  // [2, E], int32 per harness
    const float* eps        = (const float*)d_in[2];
    const float* W1         = (const float*)d_in[3];
    const float* b1         = (const float*)d_in[4];
    const float* gamma      = (const float*)d_in[5];
    const float* beta       = (const float*)d_in[6];
    const float* W2         = (const float*)d_in[7];
    const float* b2         = (const float*)d_in[8];
    float* out              = (float*)d_out;

    const int N = in_sizes[0] / NF;          // 100000
    const int E = in_sizes[1] / 2;           // 1600000

    // workspace layout: agg [N*128] f32, then stats [512] f32
    float* agg = (float*)d_ws;
    float* stats = agg + (size_t)N * NF;     // sum[128], sumsq[128], scale[128], shift[128]

    int total4 = N * NF / 4;
    init_kernel<<<(total4 + 255) / 256, 256, 0, stream>>>(x, eps, agg, stats, total4);

    long long scatterT = (long long)E * 32;
    scatter_kernel<<<(int)((scatterT + 255) / 256), 256, 0, stream>>>(x, ei, agg, E);

    int gblocks = (N + 63) / 64;
    gemm_kernel<0><<<gblocks, 256, 0, stream>>>(agg, W1, b1, out, stats, nullptr, nullptr, N);

    bn_finalize<<<1, 128, 0, stream>>>(stats, gamma, beta, stats + 256, stats + 384, N);

    gemm_kernel<1><<<gblocks, 256, 0, stream>>>(out, W2, b2, out, nullptr, stats + 256,
                                                stats + 384, N);
}

// Round 3
// 596.630 us; speedup vs baseline: 4.9006x; 4.9006x over previous
//
#include <hip/hip_runtime.h>

#define NF 128   // F_IN == F_OUT == 128

// ---------------------------------------------------------------------------
// CSR build pipeline. cursor[] doubles as deg[] during histogram.
// ---------------------------------------------------------------------------
__global__ void zero_kernel(int* __restrict__ cursor, float* __restrict__ stats, int N) {
    int i = blockIdx.x * blockDim.x + threadIdx.x;
    if (i < 512) stats[i] = 0.0f;
    if (i < N) cursor[i] = 0;
}

__global__ void hist_kernel(const int* __restrict__ ei, int* __restrict__ deg, int E) {
    int e = blockIdx.x * blockDim.x + threadIdx.x;
    if (e >= E) return;
    atomicAdd(&deg[ei[e]], 1);
}

// per-block inclusive scan of deg -> block-exclusive into rowptr, block totals
__global__ void scan1_kernel(const int* __restrict__ deg, int* __restrict__ rowptr,
                             int* __restrict__ bsum, int N) {
    __shared__ int s[256];
    int i = blockIdx.x * 256 + threadIdx.x;
    int v = (i < N) ? deg[i] : 0;
    s[threadIdx.x] = v;
    __syncthreads();
#pragma unroll
    for (int off = 1; off < 256; off <<= 1) {
        int t2 = (threadIdx.x >= off) ? s[threadIdx.x - off] : 0;
        __syncthreads();
        s[threadIdx.x] += t2;
        __syncthreads();
    }
    if (i < N) rowptr[i] = s[threadIdx.x] - v;   // block-local exclusive
    if (threadIdx.x == 255) bsum[blockIdx.x] = s[255];
}

// single block: exclusive scan of up to 1024 block sums
__global__ void scan2_kernel(const int* __restrict__ bsum, int* __restrict__ boff, int nb) {
    __shared__ int s[1024];
    int t = threadIdx.x;
    int v = (t < nb) ? bsum[t] : 0;
    s[t] = v;
    __syncthreads();
#pragma unroll
    for (int off = 1; off < 1024; off <<= 1) {
        int t2 = (t >= off) ? s[t - off] : 0;
        __syncthreads();
        s[t] += t2;
        __syncthreads();
    }
    boff[t] = s[t] - v;
}

__global__ void scan3_kernel(int* __restrict__ rowptr, int* __restrict__ cursor,
                             const int* __restrict__ boff, int N, int E) {
    int i = blockIdx.x * blockDim.x + threadIdx.x;
    if (i > N) return;
    if (i == N) { rowptr[N] = E; return; }
    int r = rowptr[i] + boff[i >> 8];
    rowptr[i] = r;
    cursor[i] = r;
}

__global__ void fill_kernel(const int* __restrict__ ei, int* __restrict__ cursor,
                            int* __restrict__ adj, int E) {
    int e = blockIdx.x * blockDim.x + threadIdx.x;
    if (e >= E) return;
    int row = ei[e];
    int col = ei[E + e];
    int slot = atomicAdd(&cursor[row], 1);
    adj[slot] = col;
}

// one wave (64 lanes) per node; lane owns a float2 feature pair.
// agg[node] = (1+eps)*x[node] + sum_{j in adj[node]} x[j]
__global__ void gather_kernel(const float* __restrict__ x, const int* __restrict__ rowptr,
                              const int* __restrict__ adj, const float* __restrict__ eps,
                              float* __restrict__ agg, int N) {
    int t = blockIdx.x * blockDim.x + threadIdx.x;
    int node = t >> 6;
    int lane = t & 63;
    if (node >= N) return;
    const float2* x2 = reinterpret_cast<const float2*>(x);
    float2 acc = x2[(long long)node * 64 + lane];
    float s = 1.0f + eps[0];
    acc.x *= s; acc.y *= s;
    int start = rowptr[node], end = rowptr[node + 1];
    for (int j = start; j < end; j++) {
        int col = adj[j];
        float2 v = x2[(long long)col * 64 + lane];
        acc.x += v.x; acc.y += v.y;
    }
    reinterpret_cast<float2*>(agg)[(long long)node * 64 + lane] = acc;
}

// ---------------------------------------------------------------------------
// Fallback path (only if ws too small): init + atomic scatter
// ---------------------------------------------------------------------------
__global__ void init_kernel(const float* __restrict__ x, const float* __restrict__ eps,
                            float* __restrict__ agg, float* __restrict__ stats, int total4) {
    int gid = blockIdx.x * blockDim.x + threadIdx.x;
    if (gid < 512) stats[gid] = 0.0f;
    if (gid >= total4) return;
    float s = 1.0f + eps[0];
    float4 v = reinterpret_cast<const float4*>(x)[gid];
    v.x *= s; v.y *= s; v.z *= s; v.w *= s;
    reinterpret_cast<float4*>(agg)[gid] = v;
}

__global__ void scatter_kernel(const float* __restrict__ x, const int* __restrict__ ei,
                               float* __restrict__ agg, int E) {
    long long gid = (long long)blockIdx.x * blockDim.x + threadIdx.x;
    int e = (int)(gid >> 5);
    if (e >= E) return;
    int c = ((int)gid & 31) << 2;
    int row = ei[e];
    int col = ei[E + e];
    const float4 v = *reinterpret_cast<const float4*>(x + (long long)col * NF + c);
    float* dst = agg + (long long)row * NF + c;
    unsafeAtomicAdd(dst + 0, v.x);
    unsafeAtomicAdd(dst + 1, v.y);
    unsafeAtomicAdd(dst + 2, v.z);
    unsafeAtomicAdd(dst + 3, v.w);
}

// ---------------------------------------------------------------------------
// SGEMM  out[n][j] = sum_k A[n][k]*W[j][k] + bias[j]
// MODE 0: plain A, fused BN-stats accumulation. MODE 1: relu(a*scale+shift) on load.
// ---------------------------------------------------------------------------
template <int MODE>
__global__ __launch_bounds__(256) void gemm_kernel(
    const float* __restrict__ A, const float* __restrict__ W,
    const float* __restrict__ bias, float* __restrict__ out,
    float* __restrict__ stats, const float* __restrict__ scale,
    const float* __restrict__ shift, int N) {
    __shared__ float As[16][68];
    __shared__ float Bs[16][132];
    __shared__ float red[16][128];

    const int t = threadIdx.x;
    const int row0 = blockIdx.x * 64;
    const int ty = t >> 4;
    const int tx = t & 15;

    float acc[4][8];
#pragma unroll
    for (int i = 0; i < 4; i++)
#pragma unroll
        for (int j = 0; j < 8; j++) acc[i][j] = 0.0f;

    for (int kt = 0; kt < 8; kt++) {
        {
            int row = t >> 2;
            int kq = t & 3;
            int r = row0 + row;
            float4 v = make_float4(0.f, 0.f, 0.f, 0.f);
            if (r < N)
                v = *reinterpret_cast<const float4*>(A + (long long)r * NF + kt * 16 + kq * 4);
            float vv[4] = {v.x, v.y, v.z, v.w};
            if (MODE == 1) {
#pragma unroll
                for (int i = 0; i < 4; i++) {
                    int k = kt * 16 + kq * 4 + i;
                    vv[i] = fmaxf(vv[i] * scale[k] + shift[k], 0.0f);
                }
            }
#pragma unroll
            for (int i = 0; i < 4; i++) As[kq * 4 + i][row] = vv[i];
        }
#pragma unroll
        for (int l = 0; l < 2; l++) {
            int li = t + l * 256;
            int j = li >> 2;
            int kq = li & 3;
            float4 w = *reinterpret_cast<const float4*>(W + j * NF + kt * 16 + kq * 4);
            float wv[4] = {w.x, w.y, w.z, w.w};
#pragma unroll
            for (int i = 0; i < 4; i++) Bs[kq * 4 + i][j] = wv[i];
        }
        __syncthreads();
#pragma unroll
        for (int kk = 0; kk < 16; kk++) {
            float4 a = *reinterpret_cast<const float4*>(&As[kk][ty * 4]);
            float4 b0 = *reinterpret_cast<const float4*>(&Bs[kk][tx * 8]);
            float4 b1 = *reinterpret_cast<const float4*>(&Bs[kk][tx * 8 + 4]);
            float av[4] = {a.x, a.y, a.z, a.w};
            float bv[8] = {b0.x, b0.y, b0.z, b0.w, b1.x, b1.y, b1.z, b1.w};
#pragma unroll
            for (int i = 0; i < 4; i++)
#pragma unroll
                for (int j = 0; j < 8; j++) acc[i][j] = fmaf(av[i], bv[j], acc[i][j]);
        }
        __syncthreads();
    }

    const int c0 = tx * 8;
    float h[4][8];
#pragma unroll
    for (int i = 0; i < 4; i++) {
        int r = row0 + ty * 4 + i;
#pragma unroll
        for (int j = 0; j < 8; j++) h[i][j] = acc[i][j] + bias[c0 + j];
        if (r < N) {
            float4 s0 = make_float4(h[i][0], h[i][1], h[i][2], h[i][3]);
            float4 s1 = make_float4(h[i][4], h[i][5], h[i][6], h[i][7]);
            *reinterpret_cast<float4*>(out + (long long)r * NF + c0) = s0;
            *reinterpret_cast<float4*>(out + (long long)r * NF + c0 + 4) = s1;
        }
    }

    if (MODE == 0) {
        float s8[8], q8[8];
#pragma unroll
        for (int j = 0; j < 8; j++) { s8[j] = 0.f; q8[j] = 0.f; }
#pragma unroll
        for (int i = 0; i < 4; i++) {
            int r = row0 + ty * 4 + i;
            if (r < N) {
#pragma unroll
                for (int j = 0; j < 8; j++) {
                    s8[j] += h[i][j];
                    q8[j] += h[i][j] * h[i][j];
                }
            }
        }
#pragma unroll
        for (int j = 0; j < 8; j++) red[ty][c0 + j] = s8[j];
        __syncthreads();
        if (t < 128) {
            float tot = 0.f;
#pragma unroll
            for (int y = 0; y < 16; y++) tot += red[y][t];
            unsafeAtomicAdd(&stats[t], tot);
        }
        __syncthreads();
#pragma unroll
        for (int j = 0; j < 8; j++) red[ty][c0 + j] = q8[j];
        __syncthreads();
        if (t < 128) {
            float tot = 0.f;
#pragma unroll
            for (int y = 0; y < 16; y++) tot += red[y][t];
            unsafeAtomicAdd(&stats[128 + t], tot);
        }
    }
}

__global__ void bn_finalize(const float* __restrict__ stats, const float* __restrict__ gamma,
                            const float* __restrict__ beta, float* __restrict__ scale,
                            float* __restrict__ shift, int N) {
    int f = threadIdx.x;
    if (f >= NF) return;
    float inv_n = 1.0f / (float)N;
    float mean = stats[f] * inv_n;
    float var = fmaxf(stats[128 + f] * inv_n - mean * mean, 0.0f);
    float s = gamma[f] * rsqrtf(var + 1e-5f);
    scale[f] = s;
    shift[f] = beta[f] - mean * s;
}

extern "C" void kernel_launch(void* const* d_in, const int* in_sizes, int n_in,
                              void* d_out, int out_size, void* d_ws, size_t ws_size,
                              hipStream_t stream) {
    const float* x     = (const float*)d_in[0];
    const int* ei      = (const int*)d_in[1];  // [2, E], int32 per harness
    const float* eps   = (const float*)d_in[2];
    const float* W1    = (const float*)d_in[3];
    const float* b1    = (const float*)d_in[4];
    const float* gamma = (const float*)d_in[5];
    const float* beta  = (const float*)d_in[6];
    const float* W2    = (const float*)d_in[7];
    const float* b2    = (const float*)d_in[8];
    float* out         = (float*)d_out;

    const int N = in_sizes[0] / NF;   // 100000
    const int E = in_sizes[1] / 2;    // 1600000

    // workspace layout
    float* agg    = (float*)d_ws;                       // N*128 f32
    float* stats  = agg + (size_t)N * NF;               // 512 f32
    int*   rowptr = (int*)(stats + 512);                // N+1
    int*   cursor = rowptr + (N + 1);                   // N (doubles as deg)
    int*   bsum   = cursor + N;                         // 1024
    int*   boff   = bsum + 1024;                        // 1024
    int*   adj    = boff + 1024;                        // E
    size_t needed = ((size_t)N * NF + 512) * 4 + ((size_t)N + 1 + N + 2048 + E) * 4;

    int gblocks = (N + 63) / 64;

    if (ws_size >= needed) {
        int nb = (N + 255) / 256;  // scan blocks (<=1024)
        zero_kernel<<<(N + 255) / 256, 256, 0, stream>>>(cursor, stats, N);
        hist_kernel<<<(E + 255) / 256, 256, 0, stream>>>(ei, cursor, E);
        scan1_kernel<<<nb, 256, 0, stream>>>(cursor, rowptr, bsum, N);
        scan2_kernel<<<1, 1024, 0, stream>>>(bsum, boff, nb);
        scan3_kernel<<<(N + 256) / 256, 256, 0, stream>>>(rowptr, cursor, boff, N, E);
        fill_kernel<<<(E + 255) / 256, 256, 0, stream>>>(ei, cursor, adj, E);
        long long gt = (long long)N * 64;
        gather_kernel<<<(int)((gt + 255) / 256), 256, 0, stream>>>(x, rowptr, adj, eps, agg, N);
    } else {
        // fallback: atomic scatter
        int total4 = N * NF / 4;
        init_kernel<<<(total4 + 255) / 256, 256, 0, stream>>>(x, eps, agg, stats, total4);
        long long st = (long long)E * 32;
        scatter_kernel<<<(int)((st + 255) / 256), 256, 0, stream>>>(x, ei, agg, E);
    }

    gemm_kernel<0><<<gblocks, 256, 0, stream>>>(agg, W1, b1, out, stats, nullptr, nullptr, N);
    bn_finalize<<<1, 128, 0, stream>>>(stats, gamma, beta, stats + 256, stats + 384, N);
    gemm_kernel<1><<<gblocks, 256, 0, stream>>>(out, W2, b2, out, nullptr, stats + 256,
                                                stats + 384, N);
}

// Round 4
// 518.034 us; speedup vs baseline: 5.6441x; 1.1517x over previous
//
#include <hip/hip_runtime.h>
#include <hip/hip_bf16.h>

#define NF 128   // F_IN == F_OUT == 128

typedef __attribute__((ext_vector_type(8))) short short8;   // 8 bf16 = 4 VGPRs (MFMA A/B frag)
typedef __attribute__((ext_vector_type(4))) float f32x4;    // MFMA C/D frag

__device__ __forceinline__ ushort f2bf(float f) {
    union { __hip_bfloat16 h; ushort u; } c;
    c.h = __float2bfloat16(f);
    return c.u;
}
__device__ __forceinline__ float bf_lo(uint u) { return __uint_as_float(u << 16); }
__device__ __forceinline__ float bf_hi(uint u) { return __uint_as_float(u & 0xffff0000u); }

// ---------------------------------------------------------------------------
// fp32 -> bf16 conversion (4 elements/thread)
// ---------------------------------------------------------------------------
__global__ void cvt_kernel(const float* __restrict__ src, ushort* __restrict__ dst, int n4) {
    int i = blockIdx.x * blockDim.x + threadIdx.x;
    if (i >= n4) return;
    float4 v = reinterpret_cast<const float4*>(src)[i];
    ushort4 o;
    o.x = f2bf(v.x); o.y = f2bf(v.y); o.z = f2bf(v.z); o.w = f2bf(v.w);
    reinterpret_cast<ushort4*>(dst)[i] = o;
}

// ---------------------------------------------------------------------------
// CSR build pipeline. cursor[] doubles as deg[] during histogram.
// ---------------------------------------------------------------------------
__global__ void zero_kernel(int* __restrict__ cursor, float* __restrict__ stats, int N) {
    int i = blockIdx.x * blockDim.x + threadIdx.x;
    if (i < 512) stats[i] = 0.0f;
    if (i < N) cursor[i] = 0;
}

__global__ void hist_kernel(const int* __restrict__ ei, int* __restrict__ deg, int E) {
    int e = blockIdx.x * blockDim.x + threadIdx.x;
    if (e >= E) return;
    atomicAdd(&deg[ei[e]], 1);
}

__global__ void scan1_kernel(const int* __restrict__ deg, int* __restrict__ rowptr,
                             int* __restrict__ bsum, int N) {
    __shared__ int s[256];
    int i = blockIdx.x * 256 + threadIdx.x;
    int v = (i < N) ? deg[i] : 0;
    s[threadIdx.x] = v;
    __syncthreads();
#pragma unroll
    for (int off = 1; off < 256; off <<= 1) {
        int t2 = (threadIdx.x >= off) ? s[threadIdx.x - off] : 0;
        __syncthreads();
        s[threadIdx.x] += t2;
        __syncthreads();
    }
    if (i < N) rowptr[i] = s[threadIdx.x] - v;
    if (threadIdx.x == 255) bsum[blockIdx.x] = s[255];
}

__global__ void scan2_kernel(const int* __restrict__ bsum, int* __restrict__ boff, int nb) {
    __shared__ int s[1024];
    int t = threadIdx.x;
    int v = (t < nb) ? bsum[t] : 0;
    s[t] = v;
    __syncthreads();
#pragma unroll
    for (int off = 1; off < 1024; off <<= 1) {
        int t2 = (t >= off) ? s[t - off] : 0;
        __syncthreads();
        s[t] += t2;
        __syncthreads();
    }
    boff[t] = s[t] - v;
}

__global__ void scan3_kernel(int* __restrict__ rowptr, int* __restrict__ cursor,
                             const int* __restrict__ boff, int N, int E) {
    int i = blockIdx.x * blockDim.x + threadIdx.x;
    if (i > N) return;
    if (i == N) { rowptr[N] = E; return; }
    int r = rowptr[i] + boff[i >> 8];
    rowptr[i] = r;
    cursor[i] = r;
}

__global__ void fill_kernel(const int* __restrict__ ei, int* __restrict__ cursor,
                            int* __restrict__ adj, int E) {
    int e = blockIdx.x * blockDim.x + threadIdx.x;
    if (e >= E) return;
    int row = ei[e];
    int col = ei[E + e];
    int slot = atomicAdd(&cursor[row], 1);
    adj[slot] = col;
}

// ---------------------------------------------------------------------------
// Gather-aggregate in bf16: one wave per node, lane owns a bf16x2 pair.
// aggb[node] = bf16( (1+eps)*x[node] + sum_{j} x[adj[j]] )  (fp32 accum)
// ---------------------------------------------------------------------------
__global__ void gather_kernel(const uint* __restrict__ xb, const int* __restrict__ rowptr,
                              const int* __restrict__ adj, const float* __restrict__ eps,
                              uint* __restrict__ aggb, int N) {
    int t = blockIdx.x * blockDim.x + threadIdx.x;
    int node = t >> 6;
    int lane = t & 63;
    if (node >= N) return;
    uint u = xb[node * 64 + lane];
    float s = 1.0f + eps[0];
    float ax = bf_lo(u) * s;
    float ay = bf_hi(u) * s;
    int beg = rowptr[node], end = rowptr[node + 1];
    for (int j = beg; j < end; j++) {
        int col = adj[j];
        uint v = xb[col * 64 + lane];
        ax += bf_lo(v);
        ay += bf_hi(v);
    }
    aggb[node * 64 + lane] = (uint)f2bf(ax) | ((uint)f2bf(ay) << 16);
}

// ---------------------------------------------------------------------------
// bf16 MFMA GEMM: out[n][j] = sum_k A[n][k]*W[j][k] + bias[j]   (K = 128)
// Block tile 128x128, full-K in LDS, 4 waves (2x2), wave = 4x4 of 16x16x32.
// MODE 0: A = aggb (bf16), fused BN sum/sumsq into stats.
// MODE 1: A = relu(h*scale+shift) from fp32 h (in d_out), written in-place.
// LDS rows padded to 136 bf16 (272 B) -> 2-way bank aliasing (free).
// ---------------------------------------------------------------------------
template <int MODE>
__global__ __launch_bounds__(256) void mgemm_kernel(
    const ushort* __restrict__ Ab, const float* __restrict__ Af,
    const ushort* __restrict__ Wb, const float* __restrict__ bias,
    float* __restrict__ out, float* __restrict__ stats,
    const float* __restrict__ scale, const float* __restrict__ shift, int N) {
    __shared__ ushort As[128 * 136];
    __shared__ ushort Bs[128 * 136];
    __shared__ float redS[256];
    __shared__ float redQ[256];

    const int t = threadIdx.x;
    const int row0 = blockIdx.x * 128;
    const int r16 = t >> 4;        // 0..15
    const int c8 = (t & 15) * 8;   // k offset

    float sc[8], sh[8];
    if (MODE == 1) {
#pragma unroll
        for (int i = 0; i < 8; i++) { sc[i] = scale[c8 + i]; sh[i] = shift[c8 + i]; }
    }

    // ---- stage A (128x128 bf16) and W (128x128 bf16) into LDS ----
#pragma unroll
    for (int it = 0; it < 8; it++) {
        int row = it * 16 + r16;
        int gr = row0 + row;
        if (MODE == 0) {
            uint4 v = make_uint4(0, 0, 0, 0);
            if (gr < N) v = *reinterpret_cast<const uint4*>(Ab + (size_t)gr * NF + c8);
            *reinterpret_cast<uint4*>(&As[row * 136 + c8]) = v;
        } else {
            float4 v0 = make_float4(0.f, 0.f, 0.f, 0.f), v1 = v0;
            if (gr < N) {
                v0 = *reinterpret_cast<const float4*>(Af + (size_t)gr * NF + c8);
                v1 = *reinterpret_cast<const float4*>(Af + (size_t)gr * NF + c8 + 4);
            }
            float vv[8] = {v0.x, v0.y, v0.z, v0.w, v1.x, v1.y, v1.z, v1.w};
#pragma unroll
            for (int i = 0; i < 8; i++) vv[i] = fmaxf(vv[i] * sc[i] + sh[i], 0.0f);
            uint4 p;
            p.x = (uint)f2bf(vv[0]) | ((uint)f2bf(vv[1]) << 16);
            p.y = (uint)f2bf(vv[2]) | ((uint)f2bf(vv[3]) << 16);
            p.z = (uint)f2bf(vv[4]) | ((uint)f2bf(vv[5]) << 16);
            p.w = (uint)f2bf(vv[6]) | ((uint)f2bf(vv[7]) << 16);
            *reinterpret_cast<uint4*>(&As[row * 136 + c8]) = p;
        }
        // W tile: j = row (exactly 128 rows)
        uint4 w = *reinterpret_cast<const uint4*>(Wb + row * NF + c8);
        *reinterpret_cast<uint4*>(&Bs[row * 136 + c8]) = w;
    }
    __syncthreads();

    const int wid = t >> 6;
    const int lane = t & 63;
    const int quad = lane >> 4;
    const int l16 = lane & 15;
    const int wm = wid >> 1;   // 0..1  row half
    const int wn = wid & 1;    // 0..1  col half

    f32x4 acc[4][4];
#pragma unroll
    for (int tm = 0; tm < 4; tm++)
#pragma unroll
        for (int tn = 0; tn < 4; tn++) acc[tm][tn] = (f32x4)(0.0f);

#pragma unroll
    for (int ks = 0; ks < 4; ks++) {
        short8 a[4], b[4];
#pragma unroll
        for (int tm = 0; tm < 4; tm++)
            a[tm] = *reinterpret_cast<const short8*>(
                &As[(wm * 64 + tm * 16 + l16) * 136 + ks * 32 + quad * 8]);
#pragma unroll
        for (int tn = 0; tn < 4; tn++)
            b[tn] = *reinterpret_cast<const short8*>(
                &Bs[(wn * 64 + tn * 16 + l16) * 136 + ks * 32 + quad * 8]);
#pragma unroll
        for (int tm = 0; tm < 4; tm++)
#pragma unroll
            for (int tn = 0; tn < 4; tn++)
                acc[tm][tn] = __builtin_amdgcn_mfma_f32_16x16x32_bf16(a[tm], b[tn],
                                                                      acc[tm][tn], 0, 0, 0);
    }

    // ---- epilogue: bias, store, fused BN stats (MODE 0) ----
    float bs[4];
#pragma unroll
    for (int tn = 0; tn < 4; tn++) bs[tn] = bias[wn * 64 + tn * 16 + l16];

    float ssum[4] = {0.f, 0.f, 0.f, 0.f}, sq[4] = {0.f, 0.f, 0.f, 0.f};
#pragma unroll
    for (int tm = 0; tm < 4; tm++) {
        int rb = wm * 64 + tm * 16 + quad * 4;
#pragma unroll
        for (int reg = 0; reg < 4; reg++) {
            int gr = row0 + rb + reg;
            bool ok = gr < N;
#pragma unroll
            for (int tn = 0; tn < 4; tn++) {
                int col = wn * 64 + tn * 16 + l16;
                float h = acc[tm][tn][reg] + bs[tn];
                if (ok) {
                    out[(size_t)gr * NF + col] = h;
                    if (MODE == 0) { ssum[tn] += h; sq[tn] += h * h; }
                }
            }
        }
    }

    if (MODE == 0) {
#pragma unroll
        for (int tn = 0; tn < 4; tn++) {
            float s = ssum[tn], q = sq[tn];
            s += __shfl_xor(s, 16); s += __shfl_xor(s, 32);
            q += __shfl_xor(q, 16); q += __shfl_xor(q, 32);
            if (quad == 0) {
                int c = wn * 64 + tn * 16 + l16;
                redS[wm * 128 + c] = s;
                redQ[wm * 128 + c] = q;
            }
        }
        __syncthreads();
        if (t < 128) {
            unsafeAtomicAdd(&stats[t], redS[t] + redS[128 + t]);
            unsafeAtomicAdd(&stats[128 + t], redQ[t] + redQ[128 + t]);
        }
    }
}

// ---------------------------------------------------------------------------
// BN finalize -> per-feature scale/shift
// ---------------------------------------------------------------------------
__global__ void bn_finalize(const float* __restrict__ stats, const float* __restrict__ gamma,
                            const float* __restrict__ beta, float* __restrict__ scale,
                            float* __restrict__ shift, int N) {
    int f = threadIdx.x;
    if (f >= NF) return;
    float inv_n = 1.0f / (float)N;
    float mean = stats[f] * inv_n;
    float var = fmaxf(stats[128 + f] * inv_n - mean * mean, 0.0f);
    float s = gamma[f] * rsqrtf(var + 1e-5f);
    scale[f] = s;
    shift[f] = beta[f] - mean * s;
}

extern "C" void kernel_launch(void* const* d_in, const int* in_sizes, int n_in,
                              void* d_out, int out_size, void* d_ws, size_t ws_size,
                              hipStream_t stream) {
    const float* x     = (const float*)d_in[0];
    const int* ei      = (const int*)d_in[1];  // [2, E], int32 per harness
    const float* eps   = (const float*)d_in[2];
    const float* W1    = (const float*)d_in[3];
    const float* b1    = (const float*)d_in[4];
    const float* gamma = (const float*)d_in[5];
    const float* beta  = (const float*)d_in[6];
    const float* W2    = (const float*)d_in[7];
    const float* b2    = (const float*)d_in[8];
    float* out         = (float*)d_out;

    const int N = in_sizes[0] / NF;   // 100000
    const int E = in_sizes[1] / 2;    // 1600000

    // workspace layout
    ushort* xb    = (ushort*)d_ws;                  // N*128 bf16
    ushort* aggb  = xb + (size_t)N * NF;            // N*128 bf16
    ushort* W1b   = aggb + (size_t)N * NF;          // 16384 bf16
    ushort* W2b   = W1b + NF * NF;                  // 16384 bf16
    float*  stats = (float*)(W2b + NF * NF);        // 512 f32: sum,sumsq,scale,shift
    int*    rowptr = (int*)(stats + 512);           // N+1
    int*    cursor = rowptr + (N + 1);              // N
    int*    bsum   = cursor + N;                    // 1024
    int*    boff   = bsum + 1024;                   // 1024
    int*    adj    = boff + 1024;                   // E

    int nb = (N + 255) / 256;

    cvt_kernel<<<(N * 32 + 255) / 256, 256, 0, stream>>>(x, xb, N * 32);
    cvt_kernel<<<16, 256, 0, stream>>>(W1, W1b, NF * NF / 4);
    cvt_kernel<<<16, 256, 0, stream>>>(W2, W2b, NF * NF / 4);

    zero_kernel<<<(N + 255) / 256, 256, 0, stream>>>(cursor, stats, N);
    hist_kernel<<<(E + 255) / 256, 256, 0, stream>>>(ei, cursor, E);
    scan1_kernel<<<nb, 256, 0, stream>>>(cursor, rowptr, bsum, N);
    scan2_kernel<<<1, 1024, 0, stream>>>(bsum, boff, nb);
    scan3_kernel<<<(N + 256) / 256, 256, 0, stream>>>(rowptr, cursor, boff, N, E);
    fill_kernel<<<(E + 255) / 256, 256, 0, stream>>>(ei, cursor, adj, E);

    long long gt = (long long)N * 64;
    gather_kernel<<<(int)((gt + 255) / 256), 256, 0, stream>>>((const uint*)xb, rowptr, adj,
                                                               eps, (uint*)aggb, N);

    int gblocks = (N + 127) / 128;
    mgemm_kernel<0><<<gblocks, 256, 0, stream>>>(aggb, nullptr, W1b, b1, out, stats,
                                                 nullptr, nullptr, N);
    bn_finalize<<<1, 128, 0, stream>>>(stats, gamma, beta, stats + 256, stats + 384, N);
    mgemm_kernel<1><<<gblocks, 256, 0, stream>>>(nullptr, out, W2b, b2, out, nullptr,
                                                 stats + 256, stats + 384, N);
}

// Round 5
// 426.095 us; speedup vs baseline: 6.8620x; 1.2158x over previous
//
#include <hip/hip_runtime.h>
#include <hip/hip_bf16.h>

#define NF 128   // F_IN == F_OUT == 128

typedef __attribute__((ext_vector_type(8))) short short8;   // 8 bf16 = 4 VGPRs (MFMA A/B frag)
typedef __attribute__((ext_vector_type(4))) float f32x4;    // MFMA C/D frag

__device__ __forceinline__ ushort f2bf(float f) {
    union { __hip_bfloat16 h; ushort u; } c;
    c.h = __float2bfloat16(f);
    return c.u;
}
__device__ __forceinline__ float bf_lo(uint u) { return __uint_as_float(u << 16); }
__device__ __forceinline__ float bf_hi(uint u) { return __uint_as_float(u & 0xffff0000u); }

// ---------------------------------------------------------------------------
// fp32 -> bf16 conversion (4 elements/thread)
// ---------------------------------------------------------------------------
__global__ void cvt_kernel(const float* __restrict__ src, ushort* __restrict__ dst, int n4) {
    int i = blockIdx.x * blockDim.x + threadIdx.x;
    if (i >= n4) return;
    float4 v = reinterpret_cast<const float4*>(src)[i];
    ushort4 o;
    o.x = f2bf(v.x); o.y = f2bf(v.y); o.z = f2bf(v.z); o.w = f2bf(v.w);
    reinterpret_cast<ushort4*>(dst)[i] = o;
}

// ---------------------------------------------------------------------------
// CSR build pipeline. cursor[] doubles as deg[] during histogram.
// ---------------------------------------------------------------------------
__global__ void zero_kernel(int* __restrict__ cursor, float* __restrict__ stats, int N) {
    int i = blockIdx.x * blockDim.x + threadIdx.x;
    if (i < 512) stats[i] = 0.0f;
    if (i < N) cursor[i] = 0;
}

__global__ void hist_kernel(const int* __restrict__ ei, int* __restrict__ deg, int E) {
    int e = blockIdx.x * blockDim.x + threadIdx.x;
    if (e >= E) return;
    atomicAdd(&deg[ei[e]], 1);
}

__global__ void scan1_kernel(const int* __restrict__ deg, int* __restrict__ rowptr,
                             int* __restrict__ bsum, int N) {
    __shared__ int s[256];
    int i = blockIdx.x * 256 + threadIdx.x;
    int v = (i < N) ? deg[i] : 0;
    s[threadIdx.x] = v;
    __syncthreads();
#pragma unroll
    for (int off = 1; off < 256; off <<= 1) {
        int t2 = (threadIdx.x >= off) ? s[threadIdx.x - off] : 0;
        __syncthreads();
        s[threadIdx.x] += t2;
        __syncthreads();
    }
    if (i < N) rowptr[i] = s[threadIdx.x] - v;
    if (threadIdx.x == 255) bsum[blockIdx.x] = s[255];
}

__global__ void scan2_kernel(const int* __restrict__ bsum, int* __restrict__ boff, int nb) {
    __shared__ int s[1024];
    int t = threadIdx.x;
    int v = (t < nb) ? bsum[t] : 0;
    s[t] = v;
    __syncthreads();
#pragma unroll
    for (int off = 1; off < 1024; off <<= 1) {
        int t2 = (t >= off) ? s[t - off] : 0;
        __syncthreads();
        s[t] += t2;
        __syncthreads();
    }
    boff[t] = s[t] - v;
}

__global__ void scan3_kernel(int* __restrict__ rowptr, int* __restrict__ cursor,
                             const int* __restrict__ boff, int N, int E) {
    int i = blockIdx.x * blockDim.x + threadIdx.x;
    if (i > N) return;
    if (i == N) { rowptr[N] = E; return; }
    int r = rowptr[i] + boff[i >> 8];
    rowptr[i] = r;
    cursor[i] = r;
}

__global__ void fill_kernel(const int* __restrict__ ei, int* __restrict__ cursor,
                            int* __restrict__ adj, int E) {
    int e = blockIdx.x * blockDim.x + threadIdx.x;
    if (e >= E) return;
    int row = ei[e];
    int col = ei[E + e];
    int slot = atomicAdd(&cursor[row], 1);
    adj[slot] = col;
}

// ---------------------------------------------------------------------------
// Gather-aggregate: 16 lanes per node (uint4 = 16B/lane -> 256B/row), so each
// wave carries 4 independent node streams; edge loop unrolled x2 => ~8
// concurrent fetch chains per wave (vs 1 in the 64-lane version).
// aggb[node] = bf16( (1+eps)*x[node] + sum_j x[adj[j]] )   (fp32 accum)
// ---------------------------------------------------------------------------
__global__ void gather_kernel(const uint4* __restrict__ xb4, const int* __restrict__ rowptr,
                              const int* __restrict__ adj, const float* __restrict__ eps,
                              uint4* __restrict__ aggb4, int N) {
    int t = blockIdx.x * blockDim.x + threadIdx.x;
    int node = t >> 4;
    int lane = t & 15;
    if (node >= N) return;
    uint4 u = xb4[(size_t)node * 16 + lane];
    float s = 1.0f + eps[0];
    float a0 = bf_lo(u.x) * s, a1 = bf_hi(u.x) * s;
    float a2 = bf_lo(u.y) * s, a3 = bf_hi(u.y) * s;
    float a4 = bf_lo(u.z) * s, a5 = bf_hi(u.z) * s;
    float a6 = bf_lo(u.w) * s, a7 = bf_hi(u.w) * s;
    int j = rowptr[node], end = rowptr[node + 1];
    for (; j + 2 <= end; j += 2) {
        int c0 = adj[j];
        int c1 = adj[j + 1];
        uint4 v0 = xb4[(size_t)c0 * 16 + lane];
        uint4 v1 = xb4[(size_t)c1 * 16 + lane];
        a0 += bf_lo(v0.x); a1 += bf_hi(v0.x);
        a2 += bf_lo(v0.y); a3 += bf_hi(v0.y);
        a4 += bf_lo(v0.z); a5 += bf_hi(v0.z);
        a6 += bf_lo(v0.w); a7 += bf_hi(v0.w);
        a0 += bf_lo(v1.x); a1 += bf_hi(v1.x);
        a2 += bf_lo(v1.y); a3 += bf_hi(v1.y);
        a4 += bf_lo(v1.z); a5 += bf_hi(v1.z);
        a6 += bf_lo(v1.w); a7 += bf_hi(v1.w);
    }
    if (j < end) {
        uint4 v0 = xb4[(size_t)adj[j] * 16 + lane];
        a0 += bf_lo(v0.x); a1 += bf_hi(v0.x);
        a2 += bf_lo(v0.y); a3 += bf_hi(v0.y);
        a4 += bf_lo(v0.z); a5 += bf_hi(v0.z);
        a6 += bf_lo(v0.w); a7 += bf_hi(v0.w);
    }
    uint4 o;
    o.x = (uint)f2bf(a0) | ((uint)f2bf(a1) << 16);
    o.y = (uint)f2bf(a2) | ((uint)f2bf(a3) << 16);
    o.z = (uint)f2bf(a4) | ((uint)f2bf(a5) << 16);
    o.w = (uint)f2bf(a6) | ((uint)f2bf(a7) << 16);
    aggb4[(size_t)node * 16 + lane] = o;
}

// ---------------------------------------------------------------------------
// bf16 MFMA GEMM: out[n][j] = sum_k A[n][k]*W[j][k] + bias[j]   (K = 128)
// Block tile 128x128, full-K in LDS, 4 waves (2x2), wave = 4x4 of 16x16x32.
// MODE 0: A = aggb (bf16), fused BN sum/sumsq into stats.
// MODE 1: A = relu(h*scale+shift) from fp32 h (in d_out), written in-place.
// LDS rows padded to 136 bf16 (272 B) -> 2-way bank aliasing (free).
// ---------------------------------------------------------------------------
template <int MODE>
__global__ __launch_bounds__(256) void mgemm_kernel(
    const ushort* __restrict__ Ab, const float* __restrict__ Af,
    const ushort* __restrict__ Wb, const float* __restrict__ bias,
    float* __restrict__ out, float* __restrict__ stats,
    const float* __restrict__ scale, const float* __restrict__ shift, int N) {
    __shared__ ushort As[128 * 136];
    __shared__ ushort Bs[128 * 136];
    __shared__ float redS[256];
    __shared__ float redQ[256];

    const int t = threadIdx.x;
    const int row0 = blockIdx.x * 128;
    const int r16 = t >> 4;        // 0..15
    const int c8 = (t & 15) * 8;   // k offset

    float sc[8], sh[8];
    if (MODE == 1) {
#pragma unroll
        for (int i = 0; i < 8; i++) { sc[i] = scale[c8 + i]; sh[i] = shift[c8 + i]; }
    }

    // ---- stage A (128x128 bf16) and W (128x128 bf16) into LDS ----
#pragma unroll
    for (int it = 0; it < 8; it++) {
        int row = it * 16 + r16;
        int gr = row0 + row;
        if (MODE == 0) {
            uint4 v = make_uint4(0, 0, 0, 0);
            if (gr < N) v = *reinterpret_cast<const uint4*>(Ab + (size_t)gr * NF + c8);
            *reinterpret_cast<uint4*>(&As[row * 136 + c8]) = v;
        } else {
            float4 v0 = make_float4(0.f, 0.f, 0.f, 0.f), v1 = v0;
            if (gr < N) {
                v0 = *reinterpret_cast<const float4*>(Af + (size_t)gr * NF + c8);
                v1 = *reinterpret_cast<const float4*>(Af + (size_t)gr * NF + c8 + 4);
            }
            float vv[8] = {v0.x, v0.y, v0.z, v0.w, v1.x, v1.y, v1.z, v1.w};
#pragma unroll
            for (int i = 0; i < 8; i++) vv[i] = fmaxf(vv[i] * sc[i] + sh[i], 0.0f);
            uint4 p;
            p.x = (uint)f2bf(vv[0]) | ((uint)f2bf(vv[1]) << 16);
            p.y = (uint)f2bf(vv[2]) | ((uint)f2bf(vv[3]) << 16);
            p.z = (uint)f2bf(vv[4]) | ((uint)f2bf(vv[5]) << 16);
            p.w = (uint)f2bf(vv[6]) | ((uint)f2bf(vv[7]) << 16);
            *reinterpret_cast<uint4*>(&As[row * 136 + c8]) = p;
        }
        // W tile: j = row (exactly 128 rows)
        uint4 w = *reinterpret_cast<const uint4*>(Wb + row * NF + c8);
        *reinterpret_cast<uint4*>(&Bs[row * 136 + c8]) = w;
    }
    __syncthreads();

    const int wid = t >> 6;
    const int lane = t & 63;
    const int quad = lane >> 4;
    const int l16 = lane & 15;
    const int wm = wid >> 1;   // 0..1  row half
    const int wn = wid & 1;    // 0..1  col half

    f32x4 acc[4][4];
#pragma unroll
    for (int tm = 0; tm < 4; tm++)
#pragma unroll
        for (int tn = 0; tn < 4; tn++) acc[tm][tn] = (f32x4)(0.0f);

#pragma unroll
    for (int ks = 0; ks < 4; ks++) {
        short8 a[4], b[4];
#pragma unroll
        for (int tm = 0; tm < 4; tm++)
            a[tm] = *reinterpret_cast<const short8*>(
                &As[(wm * 64 + tm * 16 + l16) * 136 + ks * 32 + quad * 8]);
#pragma unroll
        for (int tn = 0; tn < 4; tn++)
            b[tn] = *reinterpret_cast<const short8*>(
                &Bs[(wn * 64 + tn * 16 + l16) * 136 + ks * 32 + quad * 8]);
#pragma unroll
        for (int tm = 0; tm < 4; tm++)
#pragma unroll
            for (int tn = 0; tn < 4; tn++)
                acc[tm][tn] = __builtin_amdgcn_mfma_f32_16x16x32_bf16(a[tm], b[tn],
                                                                      acc[tm][tn], 0, 0, 0);
    }

    // ---- epilogue: bias, store, fused BN stats (MODE 0) ----
    float bs[4];
#pragma unroll
    for (int tn = 0; tn < 4; tn++) bs[tn] = bias[wn * 64 + tn * 16 + l16];

    float ssum[4] = {0.f, 0.f, 0.f, 0.f}, sq[4] = {0.f, 0.f, 0.f, 0.f};
#pragma unroll
    for (int tm = 0; tm < 4; tm++) {
        int rb = wm * 64 + tm * 16 + quad * 4;
#pragma unroll
        for (int reg = 0; reg < 4; reg++) {
            int gr = row0 + rb + reg;
            bool ok = gr < N;
#pragma unroll
            for (int tn = 0; tn < 4; tn++) {
                int col = wn * 64 + tn * 16 + l16;
                float h = acc[tm][tn][reg] + bs[tn];
                if (ok) {
                    out[(size_t)gr * NF + col] = h;
                    if (MODE == 0) { ssum[tn] += h; sq[tn] += h * h; }
                }
            }
        }
    }

    if (MODE == 0) {
#pragma unroll
        for (int tn = 0; tn < 4; tn++) {
            float s = ssum[tn], q = sq[tn];
            s += __shfl_xor(s, 16); s += __shfl_xor(s, 32);
            q += __shfl_xor(q, 16); q += __shfl_xor(q, 32);
            if (quad == 0) {
                int c = wn * 64 + tn * 16 + l16;
                redS[wm * 128 + c] = s;
                redQ[wm * 128 + c] = q;
            }
        }
        __syncthreads();
        if (t < 128) {
            unsafeAtomicAdd(&stats[t], redS[t] + redS[128 + t]);
            unsafeAtomicAdd(&stats[128 + t], redQ[t] + redQ[128 + t]);
        }
    }
}

// ---------------------------------------------------------------------------
// BN finalize -> per-feature scale/shift
// ---------------------------------------------------------------------------
__global__ void bn_finalize(const float* __restrict__ stats, const float* __restrict__ gamma,
                            const float* __restrict__ beta, float* __restrict__ scale,
                            float* __restrict__ shift, int N) {
    int f = threadIdx.x;
    if (f >= NF) return;
    float inv_n = 1.0f / (float)N;
    float mean = stats[f] * inv_n;
    float var = fmaxf(stats[128 + f] * inv_n - mean * mean, 0.0f);
    float s = gamma[f] * rsqrtf(var + 1e-5f);
    scale[f] = s;
    shift[f] = beta[f] - mean * s;
}

extern "C" void kernel_launch(void* const* d_in, const int* in_sizes, int n_in,
                              void* d_out, int out_size, void* d_ws, size_t ws_size,
                              hipStream_t stream) {
    const float* x     = (const float*)d_in[0];
    const int* ei      = (const int*)d_in[1];  // [2, E], int32 per harness
    const float* eps   = (const float*)d_in[2];
    const float* W1    = (const float*)d_in[3];
    const float* b1    = (const float*)d_in[4];
    const float* gamma = (const float*)d_in[5];
    const float* beta  = (const float*)d_in[6];
    const float* W2    = (const float*)d_in[7];
    const float* b2    = (const float*)d_in[8];
    float* out         = (float*)d_out;

    const int N = in_sizes[0] / NF;   // 100000
    const int E = in_sizes[1] / 2;    // 1600000

    // workspace layout
    ushort* xb    = (ushort*)d_ws;                  // N*128 bf16
    ushort* aggb  = xb + (size_t)N * NF;            // N*128 bf16
    ushort* W1b   = aggb + (size_t)N * NF;          // 16384 bf16
    ushort* W2b   = W1b + NF * NF;                  // 16384 bf16
    float*  stats = (float*)(W2b + NF * NF);        // 512 f32: sum,sumsq,scale,shift
    int*    rowptr = (int*)(stats + 512);           // N+1
    int*    cursor = rowptr + (N + 1);              // N
    int*    bsum   = cursor + N;                    // 1024
    int*    boff   = bsum + 1024;                   // 1024
    int*    adj    = boff + 1024;                   // E

    int nb = (N + 255) / 256;

    cvt_kernel<<<(N * 32 + 255) / 256, 256, 0, stream>>>(x, xb, N * 32);
    cvt_kernel<<<16, 256, 0, stream>>>(W1, W1b, NF * NF / 4);
    cvt_kernel<<<16, 256, 0, stream>>>(W2, W2b, NF * NF / 4);

    zero_kernel<<<(N + 255) / 256, 256, 0, stream>>>(cursor, stats, N);
    hist_kernel<<<(E + 255) / 256, 256, 0, stream>>>(ei, cursor, E);
    scan1_kernel<<<nb, 256, 0, stream>>>(cursor, rowptr, bsum, N);
    scan2_kernel<<<1, 1024, 0, stream>>>(bsum, boff, nb);
    scan3_kernel<<<(N + 256) / 256, 256, 0, stream>>>(rowptr, cursor, boff, N, E);
    fill_kernel<<<(E + 255) / 256, 256, 0, stream>>>(ei, cursor, adj, E);

    long long gt = (long long)N * 16;
    gather_kernel<<<(int)((gt + 255) / 256), 256, 0, stream>>>((const uint4*)xb, rowptr, adj,
                                                               eps, (uint4*)aggb, N);

    int gblocks = (N + 127) / 128;
    mgemm_kernel<0><<<gblocks, 256, 0, stream>>>(aggb, nullptr, W1b, b1, out, stats,
                                                 nullptr, nullptr, N);
    bn_finalize<<<1, 128, 0, stream>>>(stats, gamma, beta, stats + 256, stats + 384, N);
    mgemm_kernel<1><<<gblocks, 256, 0, stream>>>(nullptr, out, W2b, b2, out, nullptr,
                                                 stats + 256, stats + 384, N);
}

// Round 6
// 323.826 us; speedup vs baseline: 9.0290x; 1.3158x over previous
//
#include <hip/hip_runtime.h>
#include <hip/hip_bf16.h>

#define NF 128   // F_IN == F_OUT == 128

typedef __attribute__((ext_vector_type(8))) short short8;   // 8 bf16 = 4 VGPRs (MFMA A/B frag)
typedef __attribute__((ext_vector_type(4))) float f32x4;    // MFMA C/D frag

__device__ __forceinline__ ushort f2bf(float f) {
    union { __hip_bfloat16 h; ushort u; } c;
    c.h = __float2bfloat16(f);
    return c.u;
}
__device__ __forceinline__ float bf_lo(uint u) { return __uint_as_float(u << 16); }
__device__ __forceinline__ float bf_hi(uint u) { return __uint_as_float(u & 0xffff0000u); }

// ---------------------------------------------------------------------------
// fp32 -> bf16 conversion (4 elements/thread)
// ---------------------------------------------------------------------------
__global__ void cvt_kernel(const float* __restrict__ src, ushort* __restrict__ dst, int n4) {
    int i = blockIdx.x * blockDim.x + threadIdx.x;
    if (i >= n4) return;
    float4 v = reinterpret_cast<const float4*>(src)[i];
    ushort4 o;
    o.x = f2bf(v.x); o.y = f2bf(v.y); o.z = f2bf(v.z); o.w = f2bf(v.w);
    reinterpret_cast<ushort4*>(dst)[i] = o;
}

__global__ void zero_kernel(int* __restrict__ binCnt, float* __restrict__ stats) {
    int t = threadIdx.x;
    if (t < 512) stats[t] = 0.0f;
    if (t < 256) binCnt[t] = 0;
}

// ---------------------------------------------------------------------------
// Binned CSR build. Bins = 512 consecutive rows (bin = row >> 9, <=256 bins).
// PassA: per-block bin counts (LDS) -> blkCnt, bin totals -> binCnt.
// PassB: exclusive scan of binCnt -> binBase, binCursor.
// PassC: per-block chunk reservation + bin-grouped (row,col) pair scatter.
// PassD: per-bin LDS histogram -> deg (coalesced write; replaces global hist).
// scan1/2/3: exclusive scan deg -> rowptr.
// PassE: per-bin fill via LDS cursors -> adj (dense 32KB window per bin).
// ---------------------------------------------------------------------------
#define EPB 4096   // edges per block in PassA/C

__global__ void passA_kernel(const int* __restrict__ ei, int* __restrict__ blkCnt,
                             int* __restrict__ binCnt, int E) {
    __shared__ int lcnt[256];
    int t = threadIdx.x;
    lcnt[t] = 0;
    __syncthreads();
    int base = blockIdx.x * EPB;
#pragma unroll
    for (int it = 0; it < EPB / 256; it++) {
        int e = base + it * 256 + t;
        if (e < E) atomicAdd(&lcnt[ei[e] >> 9], 1);
    }
    __syncthreads();
    int c = lcnt[t];
    blkCnt[blockIdx.x * 256 + t] = c;
    if (c) atomicAdd(&binCnt[t], c);
}

__global__ void passB_kernel(const int* __restrict__ binCnt, int* __restrict__ binBase,
                             int* __restrict__ binCursor) {
    __shared__ int s[256];
    int t = threadIdx.x;
    int v = binCnt[t];
    s[t] = v;
    __syncthreads();
#pragma unroll
    for (int off = 1; off < 256; off <<= 1) {
        int t2 = (t >= off) ? s[t - off] : 0;
        __syncthreads();
        s[t] += t2;
        __syncthreads();
    }
    int excl = s[t] - v;
    binBase[t] = excl;
    binCursor[t] = excl;
}

__global__ void passC_kernel(const int* __restrict__ ei, const int* __restrict__ blkCnt,
                             int* __restrict__ binCursor, uint2* __restrict__ pair, int E) {
    __shared__ int lbase[256];
    __shared__ int lcur[256];
    int t = threadIdx.x;
    int c = blkCnt[blockIdx.x * 256 + t];
    lbase[t] = c ? atomicAdd(&binCursor[t], c) : 0;
    lcur[t] = 0;
    __syncthreads();
    int base = blockIdx.x * EPB;
#pragma unroll
    for (int it = 0; it < EPB / 256; it++) {
        int e = base + it * 256 + t;
        if (e < E) {
            int row = ei[e];
            int col = ei[E + e];
            int b = row >> 9;
            int r = atomicAdd(&lcur[b], 1);
            pair[lbase[b] + r] = make_uint2((uint)row, (uint)col);
        }
    }
}

__global__ void passD_kernel(const uint2* __restrict__ pair, const int* __restrict__ binBase,
                             const int* __restrict__ binCnt, int* __restrict__ deg, int N) {
    __shared__ int hist[512];
    int t = threadIdx.x;
    hist[t] = 0;
    hist[t + 256] = 0;
    __syncthreads();
    int b = blockIdx.x;
    int base = binBase[b], cnt = binCnt[b];
    for (int i = t; i < cnt; i += 256)
        atomicAdd(&hist[pair[base + i].x & 511], 1);
    __syncthreads();
    int g0 = b * 512 + t;
    if (g0 < N) deg[g0] = hist[t];
    if (g0 + 256 < N) deg[g0 + 256] = hist[t + 256];
}

__global__ void scan1_kernel(const int* __restrict__ deg, int* __restrict__ rowptr,
                             int* __restrict__ bsum, int N) {
    __shared__ int s[256];
    int i = blockIdx.x * 256 + threadIdx.x;
    int v = (i < N) ? deg[i] : 0;
    s[threadIdx.x] = v;
    __syncthreads();
#pragma unroll
    for (int off = 1; off < 256; off <<= 1) {
        int t2 = (threadIdx.x >= off) ? s[threadIdx.x - off] : 0;
        __syncthreads();
        s[threadIdx.x] += t2;
        __syncthreads();
    }
    if (i < N) rowptr[i] = s[threadIdx.x] - v;
    if (threadIdx.x == 255) bsum[blockIdx.x] = s[255];
}

__global__ void scan2_kernel(const int* __restrict__ bsum, int* __restrict__ boff, int nb) {
    __shared__ int s[1024];
    int t = threadIdx.x;
    int v = (t < nb) ? bsum[t] : 0;
    s[t] = v;
    __syncthreads();
#pragma unroll
    for (int off = 1; off < 1024; off <<= 1) {
        int t2 = (t >= off) ? s[t - off] : 0;
        __syncthreads();
        s[t] += t2;
        __syncthreads();
    }
    boff[t] = s[t] - v;
}

__global__ void scan3_kernel(int* __restrict__ rowptr, const int* __restrict__ boff,
                             int N, int E) {
    int i = blockIdx.x * blockDim.x + threadIdx.x;
    if (i > N) return;
    if (i == N) { rowptr[N] = E; return; }
    rowptr[i] += boff[i >> 8];
}

__global__ void passE_kernel(const uint2* __restrict__ pair, const int* __restrict__ binBase,
                             const int* __restrict__ binCnt, const int* __restrict__ rowptr,
                             int* __restrict__ adj, int N) {
    __shared__ int cur[512];
    int t = threadIdx.x;
    int b = blockIdx.x;
    int r0 = b * 512;
    if (r0 + t < N) cur[t] = rowptr[r0 + t];
    if (r0 + t + 256 < N) cur[t + 256] = rowptr[r0 + t + 256];
    __syncthreads();
    int base = binBase[b], cnt = binCnt[b];
    for (int i = t; i < cnt; i += 256) {
        uint2 p = pair[base + i];
        int slot = atomicAdd(&cur[p.x & 511], 1);
        adj[slot] = (int)p.y;
    }
}

// ---------------------------------------------------------------------------
// Gather-aggregate: 16 lanes per node (uint4/lane -> 256B/row), 4 node
// streams per wave, edge loop unrolled x2 (~8 concurrent fetch chains).
// aggb[node] = bf16( (1+eps)*x[node] + sum_j x[adj[j]] )   (fp32 accum)
// ---------------------------------------------------------------------------
__global__ void gather_kernel(const uint4* __restrict__ xb4, const int* __restrict__ rowptr,
                              const int* __restrict__ adj, const float* __restrict__ eps,
                              uint4* __restrict__ aggb4, int N) {
    int t = blockIdx.x * blockDim.x + threadIdx.x;
    int node = t >> 4;
    int lane = t & 15;
    if (node >= N) return;
    uint4 u = xb4[(size_t)node * 16 + lane];
    float s = 1.0f + eps[0];
    float a0 = bf_lo(u.x) * s, a1 = bf_hi(u.x) * s;
    float a2 = bf_lo(u.y) * s, a3 = bf_hi(u.y) * s;
    float a4 = bf_lo(u.z) * s, a5 = bf_hi(u.z) * s;
    float a6 = bf_lo(u.w) * s, a7 = bf_hi(u.w) * s;
    int j = rowptr[node], end = rowptr[node + 1];
    for (; j + 2 <= end; j += 2) {
        int c0 = adj[j];
        int c1 = adj[j + 1];
        uint4 v0 = xb4[(size_t)c0 * 16 + lane];
        uint4 v1 = xb4[(size_t)c1 * 16 + lane];
        a0 += bf_lo(v0.x); a1 += bf_hi(v0.x);
        a2 += bf_lo(v0.y); a3 += bf_hi(v0.y);
        a4 += bf_lo(v0.z); a5 += bf_hi(v0.z);
        a6 += bf_lo(v0.w); a7 += bf_hi(v0.w);
        a0 += bf_lo(v1.x); a1 += bf_hi(v1.x);
        a2 += bf_lo(v1.y); a3 += bf_hi(v1.y);
        a4 += bf_lo(v1.z); a5 += bf_hi(v1.z);
        a6 += bf_lo(v1.w); a7 += bf_hi(v1.w);
    }
    if (j < end) {
        uint4 v0 = xb4[(size_t)adj[j] * 16 + lane];
        a0 += bf_lo(v0.x); a1 += bf_hi(v0.x);
        a2 += bf_lo(v0.y); a3 += bf_hi(v0.y);
        a4 += bf_lo(v0.z); a5 += bf_hi(v0.z);
        a6 += bf_lo(v0.w); a7 += bf_hi(v0.w);
    }
    uint4 o;
    o.x = (uint)f2bf(a0) | ((uint)f2bf(a1) << 16);
    o.y = (uint)f2bf(a2) | ((uint)f2bf(a3) << 16);
    o.z = (uint)f2bf(a4) | ((uint)f2bf(a5) << 16);
    o.w = (uint)f2bf(a6) | ((uint)f2bf(a7) << 16);
    aggb4[(size_t)node * 16 + lane] = o;
}

// ---------------------------------------------------------------------------
// bf16 MFMA GEMM: out[n][j] = sum_k A[n][k]*W[j][k] + bias[j]   (K = 128)
// Block tile 128x128, full-K in LDS, 4 waves (2x2), wave = 4x4 of 16x16x32.
// MODE 0: A = aggb (bf16), fused BN sum/sumsq into stats.
// MODE 1: A = relu(h*scale+shift) from fp32 h (in d_out), written in-place.
// ---------------------------------------------------------------------------
template <int MODE>
__global__ __launch_bounds__(256) void mgemm_kernel(
    const ushort* __restrict__ Ab, const float* __restrict__ Af,
    const ushort* __restrict__ Wb, const float* __restrict__ bias,
    float* __restrict__ out, float* __restrict__ stats,
    const float* __restrict__ scale, const float* __restrict__ shift, int N) {
    __shared__ ushort As[128 * 136];
    __shared__ ushort Bs[128 * 136];
    __shared__ float redS[256];
    __shared__ float redQ[256];

    const int t = threadIdx.x;
    const int row0 = blockIdx.x * 128;
    const int r16 = t >> 4;
    const int c8 = (t & 15) * 8;

    float sc[8], sh[8];
    if (MODE == 1) {
#pragma unroll
        for (int i = 0; i < 8; i++) { sc[i] = scale[c8 + i]; sh[i] = shift[c8 + i]; }
    }

#pragma unroll
    for (int it = 0; it < 8; it++) {
        int row = it * 16 + r16;
        int gr = row0 + row;
        if (MODE == 0) {
            uint4 v = make_uint4(0, 0, 0, 0);
            if (gr < N) v = *reinterpret_cast<const uint4*>(Ab + (size_t)gr * NF + c8);
            *reinterpret_cast<uint4*>(&As[row * 136 + c8]) = v;
        } else {
            float4 v0 = make_float4(0.f, 0.f, 0.f, 0.f), v1 = v0;
            if (gr < N) {
                v0 = *reinterpret_cast<const float4*>(Af + (size_t)gr * NF + c8);
                v1 = *reinterpret_cast<const float4*>(Af + (size_t)gr * NF + c8 + 4);
            }
            float vv[8] = {v0.x, v0.y, v0.z, v0.w, v1.x, v1.y, v1.z, v1.w};
#pragma unroll
            for (int i = 0; i < 8; i++) vv[i] = fmaxf(vv[i] * sc[i] + sh[i], 0.0f);
            uint4 p;
            p.x = (uint)f2bf(vv[0]) | ((uint)f2bf(vv[1]) << 16);
            p.y = (uint)f2bf(vv[2]) | ((uint)f2bf(vv[3]) << 16);
            p.z = (uint)f2bf(vv[4]) | ((uint)f2bf(vv[5]) << 16);
            p.w = (uint)f2bf(vv[6]) | ((uint)f2bf(vv[7]) << 16);
            *reinterpret_cast<uint4*>(&As[row * 136 + c8]) = p;
        }
        uint4 w = *reinterpret_cast<const uint4*>(Wb + row * NF + c8);
        *reinterpret_cast<uint4*>(&Bs[row * 136 + c8]) = w;
    }
    __syncthreads();

    const int wid = t >> 6;
    const int lane = t & 63;
    const int quad = lane >> 4;
    const int l16 = lane & 15;
    const int wm = wid >> 1;
    const int wn = wid & 1;

    f32x4 acc[4][4];
#pragma unroll
    for (int tm = 0; tm < 4; tm++)
#pragma unroll
        for (int tn = 0; tn < 4; tn++) acc[tm][tn] = (f32x4)(0.0f);

#pragma unroll
    for (int ks = 0; ks < 4; ks++) {
        short8 a[4], b[4];
#pragma unroll
        for (int tm = 0; tm < 4; tm++)
            a[tm] = *reinterpret_cast<const short8*>(
                &As[(wm * 64 + tm * 16 + l16) * 136 + ks * 32 + quad * 8]);
#pragma unroll
        for (int tn = 0; tn < 4; tn++)
            b[tn] = *reinterpret_cast<const short8*>(
                &Bs[(wn * 64 + tn * 16 + l16) * 136 + ks * 32 + quad * 8]);
#pragma unroll
        for (int tm = 0; tm < 4; tm++)
#pragma unroll
            for (int tn = 0; tn < 4; tn++)
                acc[tm][tn] = __builtin_amdgcn_mfma_f32_16x16x32_bf16(a[tm], b[tn],
                                                                      acc[tm][tn], 0, 0, 0);
    }

    float bs[4];
#pragma unroll
    for (int tn = 0; tn < 4; tn++) bs[tn] = bias[wn * 64 + tn * 16 + l16];

    float ssum[4] = {0.f, 0.f, 0.f, 0.f}, sq[4] = {0.f, 0.f, 0.f, 0.f};
#pragma unroll
    for (int tm = 0; tm < 4; tm++) {
        int rb = wm * 64 + tm * 16 + quad * 4;
#pragma unroll
        for (int reg = 0; reg < 4; reg++) {
            int gr = row0 + rb + reg;
            bool ok = gr < N;
#pragma unroll
            for (int tn = 0; tn < 4; tn++) {
                int col = wn * 64 + tn * 16 + l16;
                float h = acc[tm][tn][reg] + bs[tn];
                if (ok) {
                    out[(size_t)gr * NF + col] = h;
                    if (MODE == 0) { ssum[tn] += h; sq[tn] += h * h; }
                }
            }
        }
    }

    if (MODE == 0) {
#pragma unroll
        for (int tn = 0; tn < 4; tn++) {
            float s = ssum[tn], q = sq[tn];
            s += __shfl_xor(s, 16); s += __shfl_xor(s, 32);
            q += __shfl_xor(q, 16); q += __shfl_xor(q, 32);
            if (quad == 0) {
                int c = wn * 64 + tn * 16 + l16;
                redS[wm * 128 + c] = s;
                redQ[wm * 128 + c] = q;
            }
        }
        __syncthreads();
        if (t < 128) {
            unsafeAtomicAdd(&stats[t], redS[t] + redS[128 + t]);
            unsafeAtomicAdd(&stats[128 + t], redQ[t] + redQ[128 + t]);
        }
    }
}

__global__ void bn_finalize(const float* __restrict__ stats, const float* __restrict__ gamma,
                            const float* __restrict__ beta, float* __restrict__ scale,
                            float* __restrict__ shift, int N) {
    int f = threadIdx.x;
    if (f >= NF) return;
    float inv_n = 1.0f / (float)N;
    float mean = stats[f] * inv_n;
    float var = fmaxf(stats[128 + f] * inv_n - mean * mean, 0.0f);
    float s = gamma[f] * rsqrtf(var + 1e-5f);
    scale[f] = s;
    shift[f] = beta[f] - mean * s;
}

extern "C" void kernel_launch(void* const* d_in, const int* in_sizes, int n_in,
                              void* d_out, int out_size, void* d_ws, size_t ws_size,
                              hipStream_t stream) {
    const float* x     = (const float*)d_in[0];
    const int* ei      = (const int*)d_in[1];  // [2, E], int32 per harness
    const float* eps   = (const float*)d_in[2];
    const float* W1    = (const float*)d_in[3];
    const float* b1    = (const float*)d_in[4];
    const float* gamma = (const float*)d_in[5];
    const float* beta  = (const float*)d_in[6];
    const float* W2    = (const float*)d_in[7];
    const float* b2    = (const float*)d_in[8];
    float* out         = (float*)d_out;

    const int N = in_sizes[0] / NF;   // 100000
    const int E = in_sizes[1] / 2;    // 1600000

    const int NB = (N + 511) >> 9;            // bins (196)
    const int nblkC = (E + EPB - 1) / EPB;    // PassA/C blocks (391)
    const int nb = (N + 255) / 256;           // scan1 blocks (391)

    // workspace layout
    ushort* xb     = (ushort*)d_ws;                 // N*128 bf16
    ushort* aggb   = xb + (size_t)N * NF;           // N*128 bf16 (pair aliases)
    ushort* W1b    = aggb + (size_t)N * NF;         // 16384 bf16
    ushort* W2b    = W1b + NF * NF;                 // 16384 bf16
    float*  stats  = (float*)(W2b + NF * NF);       // 512 f32
    int*    rowptr = (int*)(stats + 512);           // N+1
    int*    deg    = rowptr + (N + 1);              // NB*512
    int*    binCnt = deg + (size_t)NB * 512;        // 256
    int*    binBase   = binCnt + 256;               // 256
    int*    binCursor = binBase + 256;              // 256
    int*    blkCnt = binCursor + 256;               // nblkC*256
    int*    bsum   = blkCnt + (size_t)nblkC * 256;  // 1024
    int*    boff   = bsum + 1024;                   // 1024
    int*    adj    = boff + 1024;                   // E
    uint2*  pair   = (uint2*)aggb;                  // E pairs (dead until gather)

    cvt_kernel<<<(N * 32 + 255) / 256, 256, 0, stream>>>(x, xb, N * 32);
    cvt_kernel<<<16, 256, 0, stream>>>(W1, W1b, NF * NF / 4);
    cvt_kernel<<<16, 256, 0, stream>>>(W2, W2b, NF * NF / 4);

    zero_kernel<<<1, 512, 0, stream>>>(binCnt, stats);
    passA_kernel<<<nblkC, 256, 0, stream>>>(ei, blkCnt, binCnt, E);
    passB_kernel<<<1, 256, 0, stream>>>(binCnt, binBase, binCursor);
    passC_kernel<<<nblkC, 256, 0, stream>>>(ei, blkCnt, binCursor, pair, E);
    passD_kernel<<<NB, 256, 0, stream>>>(pair, binBase, binCnt, deg, N);
    scan1_kernel<<<nb, 256, 0, stream>>>(deg, rowptr, bsum, N);
    scan2_kernel<<<1, 1024, 0, stream>>>(bsum, boff, nb);
    scan3_kernel<<<(N + 256) / 256, 256, 0, stream>>>(rowptr, boff, N, E);
    passE_kernel<<<NB, 256, 0, stream>>>(pair, binBase, binCnt, rowptr, adj, N);

    long long gt = (long long)N * 16;
    gather_kernel<<<(int)((gt + 255) / 256), 256, 0, stream>>>((const uint4*)xb, rowptr, adj,
                                                               eps, (uint4*)aggb, N);

    int gblocks = (N + 127) / 128;
    mgemm_kernel<0><<<gblocks, 256, 0, stream>>>(aggb, nullptr, W1b, b1, out, stats,
                                                 nullptr, nullptr, N);
    bn_finalize<<<1, 128, 0, stream>>>(stats, gamma, beta, stats + 256, stats + 384, N);
    mgemm_kernel<1><<<gblocks, 256, 0, stream>>>(nullptr, out, W2b, b2, out, nullptr,
                                                 stats + 256, stats + 384, N);
}

// Round 7
// 301.530 us; speedup vs baseline: 9.6967x; 1.0739x over previous
//
#include <hip/hip_runtime.h>
#include <hip/hip_bf16.h>

#define NF 128   // F_IN == F_OUT == 128

typedef __attribute__((ext_vector_type(8))) short short8;   // 8 bf16 = 4 VGPRs (MFMA A/B frag)
typedef __attribute__((ext_vector_type(4))) float f32x4;    // MFMA C/D frag

__device__ __forceinline__ ushort f2bf(float f) {
    union { __hip_bfloat16 h; ushort u; } c;
    c.h = __float2bfloat16(f);
    return c.u;
}
__device__ __forceinline__ float bf_lo(uint u) { return __uint_as_float(u << 16); }
__device__ __forceinline__ float bf_hi(uint u) { return __uint_as_float(u & 0xffff0000u); }

// ---------------------------------------------------------------------------
// Kernel 1: convert x, W1, W2 to bf16; zero stats + binCnt.
// ---------------------------------------------------------------------------
__global__ void cvt_all_kernel(const float* __restrict__ x, const float* __restrict__ W1,
                               const float* __restrict__ W2, ushort* __restrict__ xb,
                               ushort* __restrict__ W1b, ushort* __restrict__ W2b,
                               float* __restrict__ stats, int* __restrict__ binCnt, int nx4) {
    int gid = blockIdx.x * blockDim.x + threadIdx.x;
    if (gid < 512) stats[gid] = 0.0f;
    if (gid < 256) binCnt[gid] = 0;
    const float* src;
    ushort* dst;
    int idx;
    if (gid < nx4) { src = x; dst = xb; idx = gid; }
    else if (gid < nx4 + 4096) { src = W1; dst = W1b; idx = gid - nx4; }
    else if (gid < nx4 + 8192) { src = W2; dst = W2b; idx = gid - nx4 - 4096; }
    else return;
    float4 v = reinterpret_cast<const float4*>(src)[idx];
    ushort4 o;
    o.x = f2bf(v.x); o.y = f2bf(v.y); o.z = f2bf(v.z); o.w = f2bf(v.w);
    reinterpret_cast<ushort4*>(dst)[idx] = o;
}

// ---------------------------------------------------------------------------
// Binned CSR build. Bin = 512 consecutive rows (row >> 9, <=256 bins).
// passA: per-block bin counts -> blkCnt, totals -> binCnt
// passB: scan binCnt -> binBase/binCursor; rowptr[N]=E
// passC: chunk reservation + bin-grouped (row,col) pair scatter
// passDE: per-bin histogram + LDS scan -> rowptr, then LDS-cursor fill -> adj
// ---------------------------------------------------------------------------
#define EPB 4096   // edges per block in passA/passC

__global__ void passA_kernel(const int* __restrict__ ei, int* __restrict__ blkCnt,
                             int* __restrict__ binCnt, int E) {
    __shared__ int lcnt[256];
    int t = threadIdx.x;
    lcnt[t] = 0;
    __syncthreads();
    int base = blockIdx.x * EPB;
#pragma unroll
    for (int it = 0; it < EPB / 256; it++) {
        int e = base + it * 256 + t;
        if (e < E) atomicAdd(&lcnt[ei[e] >> 9], 1);
    }
    __syncthreads();
    int c = lcnt[t];
    blkCnt[blockIdx.x * 256 + t] = c;
    if (c) atomicAdd(&binCnt[t], c);
}

__global__ void passB_kernel(const int* __restrict__ binCnt, int* __restrict__ binBase,
                             int* __restrict__ binCursor, int* __restrict__ rowptr,
                             int N, int E) {
    __shared__ int s[256];
    int t = threadIdx.x;
    int v = binCnt[t];
    s[t] = v;
    __syncthreads();
#pragma unroll
    for (int off = 1; off < 256; off <<= 1) {
        int t2 = (t >= off) ? s[t - off] : 0;
        __syncthreads();
        s[t] += t2;
        __syncthreads();
    }
    int excl = s[t] - v;
    binBase[t] = excl;
    binCursor[t] = excl;
    if (t == 0) rowptr[N] = E;
}

__global__ void passC_kernel(const int* __restrict__ ei, const int* __restrict__ blkCnt,
                             int* __restrict__ binCursor, uint2* __restrict__ pair, int E) {
    __shared__ int lbase[256];
    __shared__ int lcur[256];
    int t = threadIdx.x;
    int c = blkCnt[blockIdx.x * 256 + t];
    lbase[t] = c ? atomicAdd(&binCursor[t], c) : 0;
    lcur[t] = 0;
    __syncthreads();
    int base = blockIdx.x * EPB;
#pragma unroll
    for (int it = 0; it < EPB / 256; it++) {
        int e = base + it * 256 + t;
        if (e < E) {
            int row = ei[e];
            int col = ei[E + e];
            int b = row >> 9;
            int r = atomicAdd(&lcur[b], 1);
            pair[lbase[b] + r] = make_uint2((uint)row, (uint)col);
        }
    }
}

__global__ void passDE_kernel(const uint2* __restrict__ pair, const int* __restrict__ binBase,
                              const int* __restrict__ binCnt, int* __restrict__ rowptr,
                              int* __restrict__ adj, int N) {
    __shared__ int hist[512];
    __shared__ int s2[256];
    __shared__ int cur[512];
    int t = threadIdx.x;
    int b = blockIdx.x;
    hist[t] = 0;
    hist[t + 256] = 0;
    __syncthreads();
    int base = binBase[b], cnt = binCnt[b];
    for (int i = t; i < cnt; i += 256)
        atomicAdd(&hist[pair[base + i].x & 511], 1);
    __syncthreads();
    // exclusive scan over 512 (pairs-of-2 + Hillis-Steele over 256 pair sums)
    int h0 = hist[2 * t], h1 = hist[2 * t + 1];
    s2[t] = h0 + h1;
    __syncthreads();
#pragma unroll
    for (int off = 1; off < 256; off <<= 1) {
        int v = (t >= off) ? s2[t - off] : 0;
        __syncthreads();
        s2[t] += v;
        __syncthreads();
    }
    int e0 = base + s2[t] - (h0 + h1);
    int e1 = e0 + h0;
    int g0 = b * 512 + 2 * t;
    if (g0 < N) rowptr[g0] = e0;
    if (g0 + 1 < N) rowptr[g0 + 1] = e1;
    cur[2 * t] = e0;
    cur[2 * t + 1] = e1;
    __syncthreads();
    for (int i = t; i < cnt; i += 256) {
        uint2 p = pair[base + i];
        int slot = atomicAdd(&cur[p.x & 511], 1);
        adj[slot] = (int)p.y;
    }
}

// ---------------------------------------------------------------------------
// Gather-aggregate: 16 lanes per node (uint4/lane -> 256B/row), 4 node
// streams per wave, edge loop unrolled x4 (~16 concurrent fetch chains).
// aggb[node] = bf16( (1+eps)*x[node] + sum_j x[adj[j]] )   (fp32 accum)
// ---------------------------------------------------------------------------
__global__ void gather_kernel(const uint4* __restrict__ xb4, const int* __restrict__ rowptr,
                              const int* __restrict__ adj, const float* __restrict__ eps,
                              uint4* __restrict__ aggb4, int N) {
    int t = blockIdx.x * blockDim.x + threadIdx.x;
    int node = t >> 4;
    int lane = t & 15;
    if (node >= N) return;
    uint4 u = xb4[(size_t)node * 16 + lane];
    float s = 1.0f + eps[0];
    float a0 = bf_lo(u.x) * s, a1 = bf_hi(u.x) * s;
    float a2 = bf_lo(u.y) * s, a3 = bf_hi(u.y) * s;
    float a4 = bf_lo(u.z) * s, a5 = bf_hi(u.z) * s;
    float a6 = bf_lo(u.w) * s, a7 = bf_hi(u.w) * s;
    int j = rowptr[node], end = rowptr[node + 1];
    for (; j + 4 <= end; j += 4) {
        int c0 = adj[j], c1 = adj[j + 1], c2 = adj[j + 2], c3 = adj[j + 3];
        uint4 v0 = xb4[(size_t)c0 * 16 + lane];
        uint4 v1 = xb4[(size_t)c1 * 16 + lane];
        uint4 v2 = xb4[(size_t)c2 * 16 + lane];
        uint4 v3 = xb4[(size_t)c3 * 16 + lane];
        a0 += bf_lo(v0.x); a1 += bf_hi(v0.x); a2 += bf_lo(v0.y); a3 += bf_hi(v0.y);
        a4 += bf_lo(v0.z); a5 += bf_hi(v0.z); a6 += bf_lo(v0.w); a7 += bf_hi(v0.w);
        a0 += bf_lo(v1.x); a1 += bf_hi(v1.x); a2 += bf_lo(v1.y); a3 += bf_hi(v1.y);
        a4 += bf_lo(v1.z); a5 += bf_hi(v1.z); a6 += bf_lo(v1.w); a7 += bf_hi(v1.w);
        a0 += bf_lo(v2.x); a1 += bf_hi(v2.x); a2 += bf_lo(v2.y); a3 += bf_hi(v2.y);
        a4 += bf_lo(v2.z); a5 += bf_hi(v2.z); a6 += bf_lo(v2.w); a7 += bf_hi(v2.w);
        a0 += bf_lo(v3.x); a1 += bf_hi(v3.x); a2 += bf_lo(v3.y); a3 += bf_hi(v3.y);
        a4 += bf_lo(v3.z); a5 += bf_hi(v3.z); a6 += bf_lo(v3.w); a7 += bf_hi(v3.w);
    }
    for (; j < end; j++) {
        uint4 v0 = xb4[(size_t)adj[j] * 16 + lane];
        a0 += bf_lo(v0.x); a1 += bf_hi(v0.x); a2 += bf_lo(v0.y); a3 += bf_hi(v0.y);
        a4 += bf_lo(v0.z); a5 += bf_hi(v0.z); a6 += bf_lo(v0.w); a7 += bf_hi(v0.w);
    }
    uint4 o;
    o.x = (uint)f2bf(a0) | ((uint)f2bf(a1) << 16);
    o.y = (uint)f2bf(a2) | ((uint)f2bf(a3) << 16);
    o.z = (uint)f2bf(a4) | ((uint)f2bf(a5) << 16);
    o.w = (uint)f2bf(a6) | ((uint)f2bf(a7) << 16);
    aggb4[(size_t)node * 16 + lane] = o;
}

// ---------------------------------------------------------------------------
// bf16 MFMA GEMM: 128x128 block tile, full K=128 in LDS, 4 waves (2x2),
// wave = 4x4 of 16x16x32 tiles.
// MODE 0: A = aggb (bf16); h written as bf16 to hb; fused BN sum/sumsq.
// MODE 1: BN finalize in-prologue (from stats); A = relu(hb*scale+shift);
//         fp32 result to out.
// ---------------------------------------------------------------------------
template <int MODE>
__global__ __launch_bounds__(256) void mgemm_kernel(
    const ushort* __restrict__ Ab, const ushort* __restrict__ Wb,
    const float* __restrict__ bias, float* __restrict__ out,
    ushort* __restrict__ hb, float* __restrict__ stats,
    const float* __restrict__ gamma, const float* __restrict__ beta, int N) {
    __shared__ ushort As[128 * 136];
    __shared__ ushort Bs[128 * 136];
    __shared__ float redS[256];
    __shared__ float redQ[256];
    __shared__ float scL[128];
    __shared__ float shL[128];

    const int t = threadIdx.x;
    const int row0 = blockIdx.x * 128;
    const int r16 = t >> 4;
    const int c8 = (t & 15) * 8;

    if (MODE == 1 && t < 128) {
        float inv_n = 1.0f / (float)N;
        float mean = stats[t] * inv_n;
        float var = fmaxf(stats[128 + t] * inv_n - mean * mean, 0.0f);
        float s = gamma[t] * rsqrtf(var + 1e-5f);
        scL[t] = s;
        shL[t] = beta[t] - mean * s;
    }
    if (MODE == 1) __syncthreads();

    float sc[8], sh[8];
    if (MODE == 1) {
#pragma unroll
        for (int i = 0; i < 8; i++) { sc[i] = scL[c8 + i]; sh[i] = shL[c8 + i]; }
    }

#pragma unroll
    for (int it = 0; it < 8; it++) {
        int row = it * 16 + r16;
        int gr = row0 + row;
        if (MODE == 0) {
            uint4 v = make_uint4(0, 0, 0, 0);
            if (gr < N) v = *reinterpret_cast<const uint4*>(Ab + (size_t)gr * NF + c8);
            *reinterpret_cast<uint4*>(&As[row * 136 + c8]) = v;
        } else {
            uint4 v = make_uint4(0, 0, 0, 0);
            if (gr < N) v = *reinterpret_cast<const uint4*>(hb + (size_t)gr * NF + c8);
            float vv[8] = {bf_lo(v.x), bf_hi(v.x), bf_lo(v.y), bf_hi(v.y),
                           bf_lo(v.z), bf_hi(v.z), bf_lo(v.w), bf_hi(v.w)};
#pragma unroll
            for (int i = 0; i < 8; i++) vv[i] = fmaxf(vv[i] * sc[i] + sh[i], 0.0f);
            uint4 p;
            p.x = (uint)f2bf(vv[0]) | ((uint)f2bf(vv[1]) << 16);
            p.y = (uint)f2bf(vv[2]) | ((uint)f2bf(vv[3]) << 16);
            p.z = (uint)f2bf(vv[4]) | ((uint)f2bf(vv[5]) << 16);
            p.w = (uint)f2bf(vv[6]) | ((uint)f2bf(vv[7]) << 16);
            *reinterpret_cast<uint4*>(&As[row * 136 + c8]) = p;
        }
        uint4 w = *reinterpret_cast<const uint4*>(Wb + row * NF + c8);
        *reinterpret_cast<uint4*>(&Bs[row * 136 + c8]) = w;
    }
    __syncthreads();

    const int wid = t >> 6;
    const int lane = t & 63;
    const int quad = lane >> 4;
    const int l16 = lane & 15;
    const int wm = wid >> 1;
    const int wn = wid & 1;

    f32x4 acc[4][4];
#pragma unroll
    for (int tm = 0; tm < 4; tm++)
#pragma unroll
        for (int tn = 0; tn < 4; tn++) acc[tm][tn] = (f32x4)(0.0f);

#pragma unroll
    for (int ks = 0; ks < 4; ks++) {
        short8 a[4], b[4];
#pragma unroll
        for (int tm = 0; tm < 4; tm++)
            a[tm] = *reinterpret_cast<const short8*>(
                &As[(wm * 64 + tm * 16 + l16) * 136 + ks * 32 + quad * 8]);
#pragma unroll
        for (int tn = 0; tn < 4; tn++)
            b[tn] = *reinterpret_cast<const short8*>(
                &Bs[(wn * 64 + tn * 16 + l16) * 136 + ks * 32 + quad * 8]);
#pragma unroll
        for (int tm = 0; tm < 4; tm++)
#pragma unroll
            for (int tn = 0; tn < 4; tn++)
                acc[tm][tn] = __builtin_amdgcn_mfma_f32_16x16x32_bf16(a[tm], b[tn],
                                                                      acc[tm][tn], 0, 0, 0);
    }

    float bs[4];
#pragma unroll
    for (int tn = 0; tn < 4; tn++) bs[tn] = bias[wn * 64 + tn * 16 + l16];

    float ssum[4] = {0.f, 0.f, 0.f, 0.f}, sq[4] = {0.f, 0.f, 0.f, 0.f};
#pragma unroll
    for (int tm = 0; tm < 4; tm++) {
        int rb = wm * 64 + tm * 16 + quad * 4;
#pragma unroll
        for (int reg = 0; reg < 4; reg++) {
            int gr = row0 + rb + reg;
            bool ok = gr < N;
#pragma unroll
            for (int tn = 0; tn < 4; tn++) {
                int col = wn * 64 + tn * 16 + l16;
                float h = acc[tm][tn][reg] + bs[tn];
                if (ok) {
                    if (MODE == 0) {
                        hb[(size_t)gr * NF + col] = f2bf(h);
                        ssum[tn] += h;
                        sq[tn] += h * h;
                    } else {
                        out[(size_t)gr * NF + col] = h;
                    }
                }
            }
        }
    }

    if (MODE == 0) {
#pragma unroll
        for (int tn = 0; tn < 4; tn++) {
            float s = ssum[tn], q = sq[tn];
            s += __shfl_xor(s, 16); s += __shfl_xor(s, 32);
            q += __shfl_xor(q, 16); q += __shfl_xor(q, 32);
            if (quad == 0) {
                int c = wn * 64 + tn * 16 + l16;
                redS[wm * 128 + c] = s;
                redQ[wm * 128 + c] = q;
            }
        }
        __syncthreads();
        if (t < 128) {
            unsafeAtomicAdd(&stats[t], redS[t] + redS[128 + t]);
            unsafeAtomicAdd(&stats[128 + t], redQ[t] + redQ[128 + t]);
        }
    }
}

extern "C" void kernel_launch(void* const* d_in, const int* in_sizes, int n_in,
                              void* d_out, int out_size, void* d_ws, size_t ws_size,
                              hipStream_t stream) {
    const float* x     = (const float*)d_in[0];
    const int* ei      = (const int*)d_in[1];  // [2, E], int32 per harness
    const float* eps   = (const float*)d_in[2];
    const float* W1    = (const float*)d_in[3];
    const float* b1    = (const float*)d_in[4];
    const float* gamma = (const float*)d_in[5];
    const float* beta  = (const float*)d_in[6];
    const float* W2    = (const float*)d_in[7];
    const float* b2    = (const float*)d_in[8];
    float* out         = (float*)d_out;

    const int N = in_sizes[0] / NF;   // 100000
    const int E = in_sizes[1] / 2;    // 1600000

    const int NB = (N + 511) >> 9;            // bins (196)
    const int nblkC = (E + EPB - 1) / EPB;    // passA/C blocks (391)

    // workspace layout (~59 MB)
    ushort* xb     = (ushort*)d_ws;                 // N*128 bf16 (becomes hb after gather)
    ushort* aggb   = xb + (size_t)N * NF;           // N*128 bf16 (pair aliases)
    ushort* W1b    = aggb + (size_t)N * NF;         // 16384 bf16
    ushort* W2b    = W1b + NF * NF;                 // 16384 bf16
    float*  stats  = (float*)(W2b + NF * NF);       // 512 f32
    int*    rowptr = (int*)(stats + 512);           // N+1
    int*    binCnt = rowptr + (N + 1);              // 256
    int*    binBase   = binCnt + 256;               // 256
    int*    binCursor = binBase + 256;              // 256
    int*    blkCnt = binCursor + 256;               // nblkC*256
    int*    adj    = blkCnt + (size_t)nblkC * 256;  // E
    uint2*  pair   = (uint2*)aggb;                  // E pairs (dead after passDE)
    ushort* hb     = xb;                            // xb dead after gather

    int nx4 = N * 32;
    cvt_all_kernel<<<(nx4 + 8192 + 255) / 256, 256, 0, stream>>>(x, W1, W2, xb, W1b, W2b,
                                                                 stats, binCnt, nx4);
    passA_kernel<<<nblkC, 256, 0, stream>>>(ei, blkCnt, binCnt, E);
    passB_kernel<<<1, 256, 0, stream>>>(binCnt, binBase, binCursor, rowptr, N, E);
    passC_kernel<<<nblkC, 256, 0, stream>>>(ei, blkCnt, binCursor, pair, E);
    passDE_kernel<<<NB, 256, 0, stream>>>(pair, binBase, binCnt, rowptr, adj, N);

    long long gt = (long long)N * 16;
    gather_kernel<<<(int)((gt + 255) / 256), 256, 0, stream>>>((const uint4*)xb, rowptr, adj,
                                                               eps, (uint4*)aggb, N);

    int gblocks = (N + 127) / 128;
    mgemm_kernel<0><<<gblocks, 256, 0, stream>>>(aggb, W1b, b1, out, hb, stats,
                                                 nullptr, nullptr, N);
    mgemm_kernel<1><<<gblocks, 256, 0, stream>>>(nullptr, W2b, b2, out, hb, stats,
                                                 gamma, beta, N);
}

// Round 8
// 289.790 us; speedup vs baseline: 10.0895x; 1.0405x over previous
//
#include <hip/hip_runtime.h>
#include <hip/hip_bf16.h>

#define NF 128   // F_IN == F_OUT == 128

typedef __attribute__((ext_vector_type(8))) short short8;   // 8 bf16 = 4 VGPRs (MFMA A/B frag)
typedef __attribute__((ext_vector_type(4))) float f32x4;    // MFMA C/D frag

__device__ __forceinline__ ushort f2bf(float f) {
    union { __hip_bfloat16 h; ushort u; } c;
    c.h = __float2bfloat16(f);
    return c.u;
}
__device__ __forceinline__ float bf_lo(uint u) { return __uint_as_float(u << 16); }
__device__ __forceinline__ float bf_hi(uint u) { return __uint_as_float(u & 0xffff0000u); }

// ---------------------------------------------------------------------------
// Kernel 1: convert x, W1, W2 to bf16; zero stats + binCnt + binOff.
// ---------------------------------------------------------------------------
__global__ void cvt_all_kernel(const float* __restrict__ x, const float* __restrict__ W1,
                               const float* __restrict__ W2, ushort* __restrict__ xb,
                               ushort* __restrict__ W1b, ushort* __restrict__ W2b,
                               float* __restrict__ stats, int* __restrict__ binCnt,
                               int* __restrict__ binOff, int nx4) {
    int gid = blockIdx.x * blockDim.x + threadIdx.x;
    if (gid < 512) stats[gid] = 0.0f;
    if (gid < 256) { binCnt[gid] = 0; binOff[gid] = 0; }
    const float* src;
    ushort* dst;
    int idx;
    if (gid < nx4) { src = x; dst = xb; idx = gid; }
    else if (gid < nx4 + 4096) { src = W1; dst = W1b; idx = gid - nx4; }
    else if (gid < nx4 + 8192) { src = W2; dst = W2b; idx = gid - nx4 - 4096; }
    else return;
    float4 v = reinterpret_cast<const float4*>(src)[idx];
    ushort4 o;
    o.x = f2bf(v.x); o.y = f2bf(v.y); o.z = f2bf(v.z); o.w = f2bf(v.w);
    reinterpret_cast<ushort4*>(dst)[idx] = o;
}

// ---------------------------------------------------------------------------
// Binned CSR build. Bin = 512 consecutive rows (row >> 9, <=256 bins).
// passA: per-block LDS bin counts -> atomic binCnt totals
// passC: block-local counting sort of 4096 edges by bin in LDS, chunk
//        reservation via binOff atomics, coalesced bin-grouped pair write
// passDE: per-bin histogram + LDS scan -> rowptr, LDS-cursor fill -> adj
// ---------------------------------------------------------------------------
#define EPB 4096   // edges per block in passA/passC

__global__ void passA_kernel(const int* __restrict__ ei, int* __restrict__ binCnt, int E) {
    __shared__ int lcnt[256];
    int t = threadIdx.x;
    lcnt[t] = 0;
    __syncthreads();
    int base = blockIdx.x * EPB;
#pragma unroll
    for (int it = 0; it < EPB / 256; it++) {
        int e = base + it * 256 + t;
        if (e < E) atomicAdd(&lcnt[ei[e] >> 9], 1);
    }
    __syncthreads();
    int c = lcnt[t];
    if (c) atomicAdd(&binCnt[t], c);
}

__global__ void passC_kernel(const int* __restrict__ ei, const int* __restrict__ binCnt,
                             int* __restrict__ binOff, uint2* __restrict__ pair, int E) {
    __shared__ uint2 sorted[EPB];   // 32 KB
    __shared__ int lcnt[256];
    __shared__ int lofs[256];
    __shared__ int scanB[256];
    __shared__ int lcur[256];
    __shared__ int gdelta[256];
    int t = threadIdx.x;
    lcnt[t] = 0;
    lcur[t] = 0;
    __syncthreads();
    int base = blockIdx.x * EPB;
    int rows[EPB / 256], cols[EPB / 256];
#pragma unroll
    for (int it = 0; it < EPB / 256; it++) {
        int e = base + it * 256 + t;
        rows[it] = (e < E) ? ei[e] : -1;
        cols[it] = (e < E) ? ei[E + e] : 0;
        if (rows[it] >= 0) atomicAdd(&lcnt[rows[it] >> 9], 1);
    }
    __syncthreads();
    // scan1: block-local exclusive offsets per bin
    int v = lcnt[t];
    lofs[t] = v;
    // scan2: binBase = exclusive scan of global binCnt
    int bc = binCnt[t];
    scanB[t] = bc;
    __syncthreads();
#pragma unroll
    for (int off = 1; off < 256; off <<= 1) {
        int u1 = (t >= off) ? lofs[t - off] : 0;
        int u2 = (t >= off) ? scanB[t - off] : 0;
        __syncthreads();
        lofs[t] += u1;
        scanB[t] += u2;
        __syncthreads();
    }
    int myOfs = lofs[t] - v;        // block-local exclusive
    int binBase_t = scanB[t] - bc;  // global bin start
    int g = v ? atomicAdd(&binOff[t], v) : 0;  // chunk reservation within bin
    __syncthreads();
    lofs[t] = myOfs;
    gdelta[t] = binBase_t + g - myOfs;
    __syncthreads();
    // placement: counting sort into LDS
#pragma unroll
    for (int it = 0; it < EPB / 256; it++) {
        if (rows[it] >= 0) {
            int b = rows[it] >> 9;
            int p = lofs[b] + atomicAdd(&lcur[b], 1);
            sorted[p] = make_uint2((uint)rows[it], (uint)cols[it]);
        }
    }
    __syncthreads();
    // coalesced write: consecutive i -> consecutive global within bin runs
    int nvalid = min(EPB, E - base);
    for (int i = t; i < nvalid; i += 256) {
        uint2 pr = sorted[i];
        pair[gdelta[pr.x >> 9] + i] = pr;
    }
}

__global__ void passDE_kernel(const uint2* __restrict__ pair, const int* __restrict__ binCnt,
                              int* __restrict__ rowptr, int* __restrict__ adj, int N, int E) {
    __shared__ int hist[512];
    __shared__ int s2[256];
    __shared__ int cur[512];
    int t = threadIdx.x;
    int b = blockIdx.x;
    hist[t] = 0;
    hist[t + 256] = 0;
    // binBase[b] = sum of binCnt[0..b-1] via block reduction
    s2[t] = (t < b) ? binCnt[t] : 0;
    __syncthreads();
#pragma unroll
    for (int off = 128; off > 0; off >>= 1) {
        if (t < off) s2[t] += s2[t + off];
        __syncthreads();
    }
    int base = s2[0];
    int cnt = binCnt[b];
    __syncthreads();
    for (int i = t; i < cnt; i += 256)
        atomicAdd(&hist[pair[base + i].x & 511], 1);
    __syncthreads();
    // exclusive scan over 512 (pairs-of-2 + Hillis-Steele over 256 pair sums)
    int h0 = hist[2 * t], h1 = hist[2 * t + 1];
    s2[t] = h0 + h1;
    __syncthreads();
#pragma unroll
    for (int off = 1; off < 256; off <<= 1) {
        int u = (t >= off) ? s2[t - off] : 0;
        __syncthreads();
        s2[t] += u;
        __syncthreads();
    }
    int e0 = base + s2[t] - (h0 + h1);
    int e1 = e0 + h0;
    int g0 = b * 512 + 2 * t;
    if (g0 < N) rowptr[g0] = e0;
    if (g0 + 1 < N) rowptr[g0 + 1] = e1;
    if (t == 0 && b == gridDim.x - 1) rowptr[N] = E;
    cur[2 * t] = e0;
    cur[2 * t + 1] = e1;
    __syncthreads();
    for (int i = t; i < cnt; i += 256) {
        uint2 p = pair[base + i];
        int slot = atomicAdd(&cur[p.x & 511], 1);
        adj[slot] = (int)p.y;
    }
}

// ---------------------------------------------------------------------------
// Gather-aggregate: 16 lanes per node (uint4/lane -> 256B/row), 4 node
// streams per wave, edge loop unrolled x4 (~16 concurrent fetch chains).
// aggb[node] = bf16( (1+eps)*x[node] + sum_j x[adj[j]] )   (fp32 accum)
// ---------------------------------------------------------------------------
__global__ void gather_kernel(const uint4* __restrict__ xb4, const int* __restrict__ rowptr,
                              const int* __restrict__ adj, const float* __restrict__ eps,
                              uint4* __restrict__ aggb4, int N) {
    int t = blockIdx.x * blockDim.x + threadIdx.x;
    int node = t >> 4;
    int lane = t & 15;
    if (node >= N) return;
    uint4 u = xb4[(size_t)node * 16 + lane];
    float s = 1.0f + eps[0];
    float a0 = bf_lo(u.x) * s, a1 = bf_hi(u.x) * s;
    float a2 = bf_lo(u.y) * s, a3 = bf_hi(u.y) * s;
    float a4 = bf_lo(u.z) * s, a5 = bf_hi(u.z) * s;
    float a6 = bf_lo(u.w) * s, a7 = bf_hi(u.w) * s;
    int j = rowptr[node], end = rowptr[node + 1];
    for (; j + 4 <= end; j += 4) {
        int c0 = adj[j], c1 = adj[j + 1], c2 = adj[j + 2], c3 = adj[j + 3];
        uint4 v0 = xb4[(size_t)c0 * 16 + lane];
        uint4 v1 = xb4[(size_t)c1 * 16 + lane];
        uint4 v2 = xb4[(size_t)c2 * 16 + lane];
        uint4 v3 = xb4[(size_t)c3 * 16 + lane];
        a0 += bf_lo(v0.x); a1 += bf_hi(v0.x); a2 += bf_lo(v0.y); a3 += bf_hi(v0.y);
        a4 += bf_lo(v0.z); a5 += bf_hi(v0.z); a6 += bf_lo(v0.w); a7 += bf_hi(v0.w);
        a0 += bf_lo(v1.x); a1 += bf_hi(v1.x); a2 += bf_lo(v1.y); a3 += bf_hi(v1.y);
        a4 += bf_lo(v1.z); a5 += bf_hi(v1.z); a6 += bf_lo(v1.w); a7 += bf_hi(v1.w);
        a0 += bf_lo(v2.x); a1 += bf_hi(v2.x); a2 += bf_lo(v2.y); a3 += bf_hi(v2.y);
        a4 += bf_lo(v2.z); a5 += bf_hi(v2.z); a6 += bf_lo(v2.w); a7 += bf_hi(v2.w);
        a0 += bf_lo(v3.x); a1 += bf_hi(v3.x); a2 += bf_lo(v3.y); a3 += bf_hi(v3.y);
        a4 += bf_lo(v3.z); a5 += bf_hi(v3.z); a6 += bf_lo(v3.w); a7 += bf_hi(v3.w);
    }
    for (; j < end; j++) {
        uint4 v0 = xb4[(size_t)adj[j] * 16 + lane];
        a0 += bf_lo(v0.x); a1 += bf_hi(v0.x); a2 += bf_lo(v0.y); a3 += bf_hi(v0.y);
        a4 += bf_lo(v0.z); a5 += bf_hi(v0.z); a6 += bf_lo(v0.w); a7 += bf_hi(v0.w);
    }
    uint4 o;
    o.x = (uint)f2bf(a0) | ((uint)f2bf(a1) << 16);
    o.y = (uint)f2bf(a2) | ((uint)f2bf(a3) << 16);
    o.z = (uint)f2bf(a4) | ((uint)f2bf(a5) << 16);
    o.w = (uint)f2bf(a6) | ((uint)f2bf(a7) << 16);
    aggb4[(size_t)node * 16 + lane] = o;
}

// ---------------------------------------------------------------------------
// bf16 MFMA GEMM: 128x128 block tile, full K=128 in LDS, 4 waves (2x2),
// wave = 4x4 of 16x16x32 tiles.
// MODE 0: A = aggb (bf16); h written as bf16 to hb; fused BN sum/sumsq.
// MODE 1: BN finalize in-prologue (from stats); A = relu(hb*scale+shift);
//         fp32 result to out.
// ---------------------------------------------------------------------------
template <int MODE>
__global__ __launch_bounds__(256) void mgemm_kernel(
    const ushort* __restrict__ Ab, const ushort* __restrict__ Wb,
    const float* __restrict__ bias, float* __restrict__ out,
    ushort* __restrict__ hb, float* __restrict__ stats,
    const float* __restrict__ gamma, const float* __restrict__ beta, int N) {
    __shared__ ushort As[128 * 136];
    __shared__ ushort Bs[128 * 136];
    __shared__ float redS[256];
    __shared__ float redQ[256];
    __shared__ float scL[128];
    __shared__ float shL[128];

    const int t = threadIdx.x;
    const int row0 = blockIdx.x * 128;
    const int r16 = t >> 4;
    const int c8 = (t & 15) * 8;

    if (MODE == 1 && t < 128) {
        float inv_n = 1.0f / (float)N;
        float mean = stats[t] * inv_n;
        float var = fmaxf(stats[128 + t] * inv_n - mean * mean, 0.0f);
        float s = gamma[t] * rsqrtf(var + 1e-5f);
        scL[t] = s;
        shL[t] = beta[t] - mean * s;
    }
    if (MODE == 1) __syncthreads();

    float sc[8], sh[8];
    if (MODE == 1) {
#pragma unroll
        for (int i = 0; i < 8; i++) { sc[i] = scL[c8 + i]; sh[i] = shL[c8 + i]; }
    }

#pragma unroll
    for (int it = 0; it < 8; it++) {
        int row = it * 16 + r16;
        int gr = row0 + row;
        if (MODE == 0) {
            uint4 v = make_uint4(0, 0, 0, 0);
            if (gr < N) v = *reinterpret_cast<const uint4*>(Ab + (size_t)gr * NF + c8);
            *reinterpret_cast<uint4*>(&As[row * 136 + c8]) = v;
        } else {
            uint4 v = make_uint4(0, 0, 0, 0);
            if (gr < N) v = *reinterpret_cast<const uint4*>(hb + (size_t)gr * NF + c8);
            float vv[8] = {bf_lo(v.x), bf_hi(v.x), bf_lo(v.y), bf_hi(v.y),
                           bf_lo(v.z), bf_hi(v.z), bf_lo(v.w), bf_hi(v.w)};
#pragma unroll
            for (int i = 0; i < 8; i++) vv[i] = fmaxf(vv[i] * sc[i] + sh[i], 0.0f);
            uint4 p;
            p.x = (uint)f2bf(vv[0]) | ((uint)f2bf(vv[1]) << 16);
            p.y = (uint)f2bf(vv[2]) | ((uint)f2bf(vv[3]) << 16);
            p.z = (uint)f2bf(vv[4]) | ((uint)f2bf(vv[5]) << 16);
            p.w = (uint)f2bf(vv[6]) | ((uint)f2bf(vv[7]) << 16);
            *reinterpret_cast<uint4*>(&As[row * 136 + c8]) = p;
        }
        uint4 w = *reinterpret_cast<const uint4*>(Wb + row * NF + c8);
        *reinterpret_cast<uint4*>(&Bs[row * 136 + c8]) = w;
    }
    __syncthreads();

    const int wid = t >> 6;
    const int lane = t & 63;
    const int quad = lane >> 4;
    const int l16 = lane & 15;
    const int wm = wid >> 1;
    const int wn = wid & 1;

    f32x4 acc[4][4];
#pragma unroll
    for (int tm = 0; tm < 4; tm++)
#pragma unroll
        for (int tn = 0; tn < 4; tn++) acc[tm][tn] = (f32x4)(0.0f);

#pragma unroll
    for (int ks = 0; ks < 4; ks++) {
        short8 a[4], b[4];
#pragma unroll
        for (int tm = 0; tm < 4; tm++)
            a[tm] = *reinterpret_cast<const short8*>(
                &As[(wm * 64 + tm * 16 + l16) * 136 + ks * 32 + quad * 8]);
#pragma unroll
        for (int tn = 0; tn < 4; tn++)
            b[tn] = *reinterpret_cast<const short8*>(
                &Bs[(wn * 64 + tn * 16 + l16) * 136 + ks * 32 + quad * 8]);
#pragma unroll
        for (int tm = 0; tm < 4; tm++)
#pragma unroll
            for (int tn = 0; tn < 4; tn++)
                acc[tm][tn] = __builtin_amdgcn_mfma_f32_16x16x32_bf16(a[tm], b[tn],
                                                                      acc[tm][tn], 0, 0, 0);
    }

    float bs[4];
#pragma unroll
    for (int tn = 0; tn < 4; tn++) bs[tn] = bias[wn * 64 + tn * 16 + l16];

    float ssum[4] = {0.f, 0.f, 0.f, 0.f}, sq[4] = {0.f, 0.f, 0.f, 0.f};
#pragma unroll
    for (int tm = 0; tm < 4; tm++) {
        int rb = wm * 64 + tm * 16 + quad * 4;
#pragma unroll
        for (int reg = 0; reg < 4; reg++) {
            int gr = row0 + rb + reg;
            bool ok = gr < N;
#pragma unroll
            for (int tn = 0; tn < 4; tn++) {
                int col = wn * 64 + tn * 16 + l16;
                float h = acc[tm][tn][reg] + bs[tn];
                if (ok) {
                    if (MODE == 0) {
                        hb[(size_t)gr * NF + col] = f2bf(h);
                        ssum[tn] += h;
                        sq[tn] += h * h;
                    } else {
                        out[(size_t)gr * NF + col] = h;
                    }
                }
            }
        }
    }

    if (MODE == 0) {
#pragma unroll
        for (int tn = 0; tn < 4; tn++) {
            float s = ssum[tn], q = sq[tn];
            s += __shfl_xor(s, 16); s += __shfl_xor(s, 32);
            q += __shfl_xor(q, 16); q += __shfl_xor(q, 32);
            if (quad == 0) {
                int c = wn * 64 + tn * 16 + l16;
                redS[wm * 128 + c] = s;
                redQ[wm * 128 + c] = q;
            }
        }
        __syncthreads();
        if (t < 128) {
            unsafeAtomicAdd(&stats[t], redS[t] + redS[128 + t]);
            unsafeAtomicAdd(&stats[128 + t], redQ[t] + redQ[128 + t]);
        }
    }
}

extern "C" void kernel_launch(void* const* d_in, const int* in_sizes, int n_in,
                              void* d_out, int out_size, void* d_ws, size_t ws_size,
                              hipStream_t stream) {
    const float* x     = (const float*)d_in[0];
    const int* ei      = (const int*)d_in[1];  // [2, E], int32 per harness
    const float* eps   = (const float*)d_in[2];
    const float* W1    = (const float*)d_in[3];
    const float* b1    = (const float*)d_in[4];
    const float* gamma = (const float*)d_in[5];
    const float* beta  = (const float*)d_in[6];
    const float* W2    = (const float*)d_in[7];
    const float* b2    = (const float*)d_in[8];
    float* out         = (float*)d_out;

    const int N = in_sizes[0] / NF;   // 100000
    const int E = in_sizes[1] / 2;    // 1600000

    const int NB = (N + 511) >> 9;            // bins (196)
    const int nblkC = (E + EPB - 1) / EPB;    // passA/C blocks (391)

    // workspace layout (~58 MB)
    ushort* xb     = (ushort*)d_ws;                 // N*128 bf16 (becomes hb after gather)
    ushort* aggb   = xb + (size_t)N * NF;           // N*128 bf16 (pair aliases)
    ushort* W1b    = aggb + (size_t)N * NF;         // 16384 bf16
    ushort* W2b    = W1b + NF * NF;                 // 16384 bf16
    float*  stats  = (float*)(W2b + NF * NF);       // 512 f32
    int*    rowptr = (int*)(stats + 512);           // N+1
    int*    binCnt = rowptr + (N + 1);              // 256
    int*    binOff = binCnt + 256;                  // 256
    int*    adj    = binOff + 256;                  // E
    uint2*  pair   = (uint2*)aggb;                  // E pairs (dead after passDE)
    ushort* hb     = xb;                            // xb dead after gather

    int nx4 = N * 32;
    cvt_all_kernel<<<(nx4 + 8192 + 255) / 256, 256, 0, stream>>>(x, W1, W2, xb, W1b, W2b,
                                                                 stats, binCnt, binOff, nx4);
    passA_kernel<<<nblkC, 256, 0, stream>>>(ei, binCnt, E);
    passC_kernel<<<nblkC, 256, 0, stream>>>(ei, binCnt, binOff, pair, E);
    passDE_kernel<<<NB, 256, 0, stream>>>(pair, binCnt, rowptr, adj, N, E);

    long long gt = (long long)N * 16;
    gather_kernel<<<(int)((gt + 255) / 256), 256, 0, stream>>>((const uint4*)xb, rowptr, adj,
                                                               eps, (uint4*)aggb, N);

    int gblocks = (N + 127) / 128;
    mgemm_kernel<0><<<gblocks, 256, 0, stream>>>(aggb, W1b, b1, out, hb, stats,
                                                 nullptr, nullptr, N);
    mgemm_kernel<1><<<gblocks, 256, 0, stream>>>(nullptr, W2b, b2, out, hb, stats,
                                                 gamma, beta, N);
}

// Round 9
// 277.994 us; speedup vs baseline: 10.5177x; 1.0424x over previous
//
#include <hip/hip_runtime.h>
#include <hip/hip_bf16.h>

#define NF 128   // F_IN == F_OUT == 128

typedef __attribute__((ext_vector_type(8))) short short8;   // 8 bf16 = 4 VGPRs (MFMA A/B frag)
typedef __attribute__((ext_vector_type(4))) float f32x4;    // MFMA C/D frag

__device__ __forceinline__ ushort f2bf(float f) {
    union { __hip_bfloat16 h; ushort u; } c;
    c.h = __float2bfloat16(f);
    return c.u;
}
__device__ __forceinline__ float bf_lo(uint u) { return __uint_as_float(u << 16); }
__device__ __forceinline__ float bf_hi(uint u) { return __uint_as_float(u & 0xffff0000u); }

#define EPB 4096   // edges per block in hist/passC

// ---------------------------------------------------------------------------
// Kernel 1: convert x, W1, W2 to bf16; blocks < nblkC also histogram their
// EPB-edge slice into binCnt (bin = row>>9). binCnt/binOff/stats are zeroed
// by a hipMemsetAsync before this launch.
// ---------------------------------------------------------------------------
__global__ void cvt_hist_kernel(const float* __restrict__ x, const float* __restrict__ W1,
                                const float* __restrict__ W2, ushort* __restrict__ xb,
                                ushort* __restrict__ W1b, ushort* __restrict__ W2b,
                                const int* __restrict__ ei, int* __restrict__ binCnt,
                                int nx4, int nblkC, int E) {
    __shared__ int lcnt[256];
    int t = threadIdx.x;
    int blk = blockIdx.x;
    if (blk < nblkC) {
        lcnt[t] = 0;
        __syncthreads();
        int base = blk * EPB;
#pragma unroll
        for (int it = 0; it < EPB / 256; it++) {
            int e = base + it * 256 + t;
            if (e < E) atomicAdd(&lcnt[ei[e] >> 9], 1);
        }
        __syncthreads();
        int c = lcnt[t];
        if (c) atomicAdd(&binCnt[t], c);
    }
    int gid = blk * 256 + t;
    const float* src;
    ushort* dst;
    int idx;
    if (gid < nx4) { src = x; dst = xb; idx = gid; }
    else if (gid < nx4 + 4096) { src = W1; dst = W1b; idx = gid - nx4; }
    else if (gid < nx4 + 8192) { src = W2; dst = W2b; idx = gid - nx4 - 4096; }
    else return;
    float4 v = reinterpret_cast<const float4*>(src)[idx];
    ushort4 o;
    o.x = f2bf(v.x); o.y = f2bf(v.y); o.z = f2bf(v.z); o.w = f2bf(v.w);
    reinterpret_cast<ushort4*>(dst)[idx] = o;
}

// ---------------------------------------------------------------------------
// passC: block-local counting sort of EPB edges by bin in LDS, chunk
// reservation via binOff atomics, coalesced bin-grouped pair write.
// ---------------------------------------------------------------------------
__global__ void passC_kernel(const int* __restrict__ ei, const int* __restrict__ binCnt,
                             int* __restrict__ binOff, uint2* __restrict__ pair, int E) {
    __shared__ uint2 sorted[EPB];   // 32 KB
    __shared__ int lcnt[256];
    __shared__ int lofs[256];
    __shared__ int scanB[256];
    __shared__ int lcur[256];
    __shared__ int gdelta[256];
    int t = threadIdx.x;
    lcnt[t] = 0;
    lcur[t] = 0;
    __syncthreads();
    int base = blockIdx.x * EPB;
    int rows[EPB / 256], cols[EPB / 256];
#pragma unroll
    for (int it = 0; it < EPB / 256; it++) {
        int e = base + it * 256 + t;
        rows[it] = (e < E) ? ei[e] : -1;
        cols[it] = (e < E) ? ei[E + e] : 0;
        if (rows[it] >= 0) atomicAdd(&lcnt[rows[it] >> 9], 1);
    }
    __syncthreads();
    int v = lcnt[t];
    lofs[t] = v;
    int bc = binCnt[t];
    scanB[t] = bc;
    __syncthreads();
#pragma unroll
    for (int off = 1; off < 256; off <<= 1) {
        int u1 = (t >= off) ? lofs[t - off] : 0;
        int u2 = (t >= off) ? scanB[t - off] : 0;
        __syncthreads();
        lofs[t] += u1;
        scanB[t] += u2;
        __syncthreads();
    }
    int myOfs = lofs[t] - v;
    int binBase_t = scanB[t] - bc;
    int g = v ? atomicAdd(&binOff[t], v) : 0;
    __syncthreads();
    lofs[t] = myOfs;
    gdelta[t] = binBase_t + g - myOfs;
    __syncthreads();
#pragma unroll
    for (int it = 0; it < EPB / 256; it++) {
        if (rows[it] >= 0) {
            int b = rows[it] >> 9;
            int p = lofs[b] + atomicAdd(&lcur[b], 1);
            sorted[p] = make_uint2((uint)rows[it], (uint)cols[it]);
        }
    }
    __syncthreads();
    int nvalid = min(EPB, E - base);
    for (int i = t; i < nvalid; i += 256) {
        uint2 pr = sorted[i];
        pair[gdelta[pr.x >> 9] + i] = pr;
    }
}

// ---------------------------------------------------------------------------
// passDE: per-bin histogram + LDS scan -> rowptr, LDS-cursor fill -> adj.
// ---------------------------------------------------------------------------
__global__ void passDE_kernel(const uint2* __restrict__ pair, const int* __restrict__ binCnt,
                              int* __restrict__ rowptr, int* __restrict__ adj, int N, int E) {
    __shared__ int hist[512];
    __shared__ int s2[256];
    __shared__ int cur[512];
    int t = threadIdx.x;
    int b = blockIdx.x;
    hist[t] = 0;
    hist[t + 256] = 0;
    s2[t] = (t < b) ? binCnt[t] : 0;
    __syncthreads();
#pragma unroll
    for (int off = 128; off > 0; off >>= 1) {
        if (t < off) s2[t] += s2[t + off];
        __syncthreads();
    }
    int base = s2[0];
    int cnt = binCnt[b];
    __syncthreads();
    for (int i = t; i < cnt; i += 256)
        atomicAdd(&hist[pair[base + i].x & 511], 1);
    __syncthreads();
    int h0 = hist[2 * t], h1 = hist[2 * t + 1];
    s2[t] = h0 + h1;
    __syncthreads();
#pragma unroll
    for (int off = 1; off < 256; off <<= 1) {
        int u = (t >= off) ? s2[t - off] : 0;
        __syncthreads();
        s2[t] += u;
        __syncthreads();
    }
    int e0 = base + s2[t] - (h0 + h1);
    int e1 = e0 + h0;
    int g0 = b * 512 + 2 * t;
    if (g0 < N) rowptr[g0] = e0;
    if (g0 + 1 < N) rowptr[g0 + 1] = e1;
    if (t == 0 && b == gridDim.x - 1) rowptr[N] = E;
    cur[2 * t] = e0;
    cur[2 * t + 1] = e1;
    __syncthreads();
    for (int i = t; i < cnt; i += 256) {
        uint2 p = pair[base + i];
        int slot = atomicAdd(&cur[p.x & 511], 1);
        adj[slot] = (int)p.y;
    }
}

// ---------------------------------------------------------------------------
// Gather-aggregate: 16 lanes per node (uint4/lane -> 256B/row), 4 node
// streams per wave, edge loop unrolled x8 (+4/2/1 tail) -> ~32 concurrent
// fetch chains per wave, bounded serial tail.
// aggb[node] = bf16( (1+eps)*x[node] + sum_j x[adj[j]] )   (fp32 accum)
// ---------------------------------------------------------------------------
#define ACCV(v)                                                   \
    a0 += bf_lo((v).x); a1 += bf_hi((v).x);                       \
    a2 += bf_lo((v).y); a3 += bf_hi((v).y);                       \
    a4 += bf_lo((v).z); a5 += bf_hi((v).z);                       \
    a6 += bf_lo((v).w); a7 += bf_hi((v).w);

__global__ void gather_kernel(const uint4* __restrict__ xb4, const int* __restrict__ rowptr,
                              const int* __restrict__ adj, const float* __restrict__ eps,
                              uint4* __restrict__ aggb4, int N) {
    int t = blockIdx.x * blockDim.x + threadIdx.x;
    int node = t >> 4;
    int lane = t & 15;
    if (node >= N) return;
    uint4 u = xb4[(size_t)node * 16 + lane];
    float s = 1.0f + eps[0];
    float a0 = bf_lo(u.x) * s, a1 = bf_hi(u.x) * s;
    float a2 = bf_lo(u.y) * s, a3 = bf_hi(u.y) * s;
    float a4 = bf_lo(u.z) * s, a5 = bf_hi(u.z) * s;
    float a6 = bf_lo(u.w) * s, a7 = bf_hi(u.w) * s;
    int j = rowptr[node], end = rowptr[node + 1];
    for (; j + 8 <= end; j += 8) {
        int c0 = adj[j],     c1 = adj[j + 1], c2 = adj[j + 2], c3 = adj[j + 3];
        int c4 = adj[j + 4], c5 = adj[j + 5], c6 = adj[j + 6], c7 = adj[j + 7];
        uint4 v0 = xb4[(size_t)c0 * 16 + lane];
        uint4 v1 = xb4[(size_t)c1 * 16 + lane];
        uint4 v2 = xb4[(size_t)c2 * 16 + lane];
        uint4 v3 = xb4[(size_t)c3 * 16 + lane];
        uint4 v4 = xb4[(size_t)c4 * 16 + lane];
        uint4 v5 = xb4[(size_t)c5 * 16 + lane];
        uint4 v6 = xb4[(size_t)c6 * 16 + lane];
        uint4 v7 = xb4[(size_t)c7 * 16 + lane];
        ACCV(v0) ACCV(v1) ACCV(v2) ACCV(v3)
        ACCV(v4) ACCV(v5) ACCV(v6) ACCV(v7)
    }
    if (j + 4 <= end) {
        int c0 = adj[j], c1 = adj[j + 1], c2 = adj[j + 2], c3 = adj[j + 3];
        uint4 v0 = xb4[(size_t)c0 * 16 + lane];
        uint4 v1 = xb4[(size_t)c1 * 16 + lane];
        uint4 v2 = xb4[(size_t)c2 * 16 + lane];
        uint4 v3 = xb4[(size_t)c3 * 16 + lane];
        ACCV(v0) ACCV(v1) ACCV(v2) ACCV(v3)
        j += 4;
    }
    if (j + 2 <= end) {
        int c0 = adj[j], c1 = adj[j + 1];
        uint4 v0 = xb4[(size_t)c0 * 16 + lane];
        uint4 v1 = xb4[(size_t)c1 * 16 + lane];
        ACCV(v0) ACCV(v1)
        j += 2;
    }
    if (j < end) {
        uint4 v0 = xb4[(size_t)adj[j] * 16 + lane];
        ACCV(v0)
    }
    uint4 o;
    o.x = (uint)f2bf(a0) | ((uint)f2bf(a1) << 16);
    o.y = (uint)f2bf(a2) | ((uint)f2bf(a3) << 16);
    o.z = (uint)f2bf(a4) | ((uint)f2bf(a5) << 16);
    o.w = (uint)f2bf(a6) | ((uint)f2bf(a7) << 16);
    aggb4[(size_t)node * 16 + lane] = o;
}

// ---------------------------------------------------------------------------
// bf16 MFMA GEMM: 128x128 block tile, full K=128 in LDS, 4 waves (2x2),
// wave = 4x4 of 16x16x32 tiles.
// MODE 0: A = aggb (bf16); h written as bf16 to hb; fused BN sum/sumsq.
// MODE 1: BN finalize in-prologue (from stats); A = relu(hb*scale+shift);
//         fp32 result to out.
// ---------------------------------------------------------------------------
template <int MODE>
__global__ __launch_bounds__(256) void mgemm_kernel(
    const ushort* __restrict__ Ab, const ushort* __restrict__ Wb,
    const float* __restrict__ bias, float* __restrict__ out,
    ushort* __restrict__ hb, float* __restrict__ stats,
    const float* __restrict__ gamma, const float* __restrict__ beta, int N) {
    __shared__ ushort As[128 * 136];
    __shared__ ushort Bs[128 * 136];
    __shared__ float redS[256];
    __shared__ float redQ[256];
    __shared__ float scL[128];
    __shared__ float shL[128];

    const int t = threadIdx.x;
    const int row0 = blockIdx.x * 128;
    const int r16 = t >> 4;
    const int c8 = (t & 15) * 8;

    if (MODE == 1 && t < 128) {
        float inv_n = 1.0f / (float)N;
        float mean = stats[t] * inv_n;
        float var = fmaxf(stats[128 + t] * inv_n - mean * mean, 0.0f);
        float s = gamma[t] * rsqrtf(var + 1e-5f);
        scL[t] = s;
        shL[t] = beta[t] - mean * s;
    }
    if (MODE == 1) __syncthreads();

    float sc[8], sh[8];
    if (MODE == 1) {
#pragma unroll
        for (int i = 0; i < 8; i++) { sc[i] = scL[c8 + i]; sh[i] = shL[c8 + i]; }
    }

#pragma unroll
    for (int it = 0; it < 8; it++) {
        int row = it * 16 + r16;
        int gr = row0 + row;
        if (MODE == 0) {
            uint4 v = make_uint4(0, 0, 0, 0);
            if (gr < N) v = *reinterpret_cast<const uint4*>(Ab + (size_t)gr * NF + c8);
            *reinterpret_cast<uint4*>(&As[row * 136 + c8]) = v;
        } else {
            uint4 v = make_uint4(0, 0, 0, 0);
            if (gr < N) v = *reinterpret_cast<const uint4*>(hb + (size_t)gr * NF + c8);
            float vv[8] = {bf_lo(v.x), bf_hi(v.x), bf_lo(v.y), bf_hi(v.y),
                           bf_lo(v.z), bf_hi(v.z), bf_lo(v.w), bf_hi(v.w)};
#pragma unroll
            for (int i = 0; i < 8; i++) vv[i] = fmaxf(vv[i] * sc[i] + sh[i], 0.0f);
            uint4 p;
            p.x = (uint)f2bf(vv[0]) | ((uint)f2bf(vv[1]) << 16);
            p.y = (uint)f2bf(vv[2]) | ((uint)f2bf(vv[3]) << 16);
            p.z = (uint)f2bf(vv[4]) | ((uint)f2bf(vv[5]) << 16);
            p.w = (uint)f2bf(vv[6]) | ((uint)f2bf(vv[7]) << 16);
            *reinterpret_cast<uint4*>(&As[row * 136 + c8]) = p;
        }
        uint4 w = *reinterpret_cast<const uint4*>(Wb + row * NF + c8);
        *reinterpret_cast<uint4*>(&Bs[row * 136 + c8]) = w;
    }
    __syncthreads();

    const int wid = t >> 6;
    const int lane = t & 63;
    const int quad = lane >> 4;
    const int l16 = lane & 15;
    const int wm = wid >> 1;
    const int wn = wid & 1;

    f32x4 acc[4][4];
#pragma unroll
    for (int tm = 0; tm < 4; tm++)
#pragma unroll
        for (int tn = 0; tn < 4; tn++) acc[tm][tn] = (f32x4)(0.0f);

#pragma unroll
    for (int ks = 0; ks < 4; ks++) {
        short8 a[4], b[4];
#pragma unroll
        for (int tm = 0; tm < 4; tm++)
            a[tm] = *reinterpret_cast<const short8*>(
                &As[(wm * 64 + tm * 16 + l16) * 136 + ks * 32 + quad * 8]);
#pragma unroll
        for (int tn = 0; tn < 4; tn++)
            b[tn] = *reinterpret_cast<const short8*>(
                &Bs[(wn * 64 + tn * 16 + l16) * 136 + ks * 32 + quad * 8]);
#pragma unroll
        for (int tm = 0; tm < 4; tm++)
#pragma unroll
            for (int tn = 0; tn < 4; tn++)
                acc[tm][tn] = __builtin_amdgcn_mfma_f32_16x16x32_bf16(a[tm], b[tn],
                                                                      acc[tm][tn], 0, 0, 0);
    }

    float bs[4];
#pragma unroll
    for (int tn = 0; tn < 4; tn++) bs[tn] = bias[wn * 64 + tn * 16 + l16];

    float ssum[4] = {0.f, 0.f, 0.f, 0.f}, sq[4] = {0.f, 0.f, 0.f, 0.f};
#pragma unroll
    for (int tm = 0; tm < 4; tm++) {
        int rb = wm * 64 + tm * 16 + quad * 4;
#pragma unroll
        for (int reg = 0; reg < 4; reg++) {
            int gr = row0 + rb + reg;
            bool ok = gr < N;
#pragma unroll
            for (int tn = 0; tn < 4; tn++) {
                int col = wn * 64 + tn * 16 + l16;
                float h = acc[tm][tn][reg] + bs[tn];
                if (ok) {
                    if (MODE == 0) {
                        hb[(size_t)gr * NF + col] = f2bf(h);
                        ssum[tn] += h;
                        sq[tn] += h * h;
                    } else {
                        out[(size_t)gr * NF + col] = h;
                    }
                }
            }
        }
    }

    if (MODE == 0) {
#pragma unroll
        for (int tn = 0; tn < 4; tn++) {
            float s = ssum[tn], q = sq[tn];
            s += __shfl_xor(s, 16); s += __shfl_xor(s, 32);
            q += __shfl_xor(q, 16); q += __shfl_xor(q, 32);
            if (quad == 0) {
                int c = wn * 64 + tn * 16 + l16;
                redS[wm * 128 + c] = s;
                redQ[wm * 128 + c] = q;
            }
        }
        __syncthreads();
        if (t < 128) {
            unsafeAtomicAdd(&stats[t], redS[t] + redS[128 + t]);
            unsafeAtomicAdd(&stats[128 + t], redQ[t] + redQ[128 + t]);
        }
    }
}

extern "C" void kernel_launch(void* const* d_in, const int* in_sizes, int n_in,
                              void* d_out, int out_size, void* d_ws, size_t ws_size,
                              hipStream_t stream) {
    const float* x     = (const float*)d_in[0];
    const int* ei      = (const int*)d_in[1];  // [2, E], int32 per harness
    const float* eps   = (const float*)d_in[2];
    const float* W1    = (const float*)d_in[3];
    const float* b1    = (const float*)d_in[4];
    const float* gamma = (const float*)d_in[5];
    const float* beta  = (const float*)d_in[6];
    const float* W2    = (const float*)d_in[7];
    const float* b2    = (const float*)d_in[8];
    float* out         = (float*)d_out;

    const int N = in_sizes[0] / NF;   // 100000
    const int E = in_sizes[1] / 2;    // 1600000

    const int NB = (N + 511) >> 9;            // bins (196)
    const int nblkC = (E + EPB - 1) / EPB;    // hist/passC blocks (391)

    // workspace layout (~58 MB)
    ushort* xb     = (ushort*)d_ws;                 // N*128 bf16 (becomes hb after gather)
    ushort* aggb   = xb + (size_t)N * NF;           // N*128 bf16 (pair aliases)
    ushort* W1b    = aggb + (size_t)N * NF;         // 16384 bf16
    ushort* W2b    = W1b + NF * NF;                 // 16384 bf16
    float*  stats  = (float*)(W2b + NF * NF);       // 512 f32
    int*    binCnt = (int*)(stats + 512);           // 256
    int*    binOff = binCnt + 256;                  // 256
    int*    rowptr = binOff + 256;                  // N+1
    int*    adj    = rowptr + (N + 1);              // E
    uint2*  pair   = (uint2*)aggb;                  // E pairs (dead after passDE)
    ushort* hb     = xb;                            // xb dead after gather

    // zero stats(512f) + binCnt(256) + binOff(256) = 4 KB contiguous
    hipMemsetAsync(stats, 0, 4096, stream);

    int nx4 = N * 32;
    int cvtBlocks = (nx4 + 8192 + 255) / 256;
    cvt_hist_kernel<<<cvtBlocks, 256, 0, stream>>>(x, W1, W2, xb, W1b, W2b, ei, binCnt,
                                                   nx4, nblkC, E);
    passC_kernel<<<nblkC, 256, 0, stream>>>(ei, binCnt, binOff, pair, E);
    passDE_kernel<<<NB, 256, 0, stream>>>(pair, binCnt, rowptr, adj, N, E);

    long long gt = (long long)N * 16;
    gather_kernel<<<(int)((gt + 255) / 256), 256, 0, stream>>>((const uint4*)xb, rowptr, adj,
                                                               eps, (uint4*)aggb, N);

    int gblocks = (N + 127) / 128;
    mgemm_kernel<0><<<gblocks, 256, 0, stream>>>(aggb, W1b, b1, out, hb, stats,
                                                 nullptr, nullptr, N);
    mgemm_kernel<1><<<gblocks, 256, 0, stream>>>(nullptr, W2b, b2, out, hb, stats,
                                                 gamma, beta, N);
}